// Round 1
// baseline (3477.134 us; speedup 1.0000x reference)
//
#include <hip/hip_runtime.h>

#define TT 2048
#define BB 2
#define DD 1024
#define HH 16
#define HD 64
#define FF 4096
#define EE 8
#define SS (TT*BB)     // 4096 tokens
#define CAP 1024       // 2*ceil(S/E)
#define EPSF 1.1920929e-07f

// ---------------- LayerNorm: one row (D=1024) per block, 256 thr x float4 ----
__global__ __launch_bounds__(256) void ln_kernel(const float* __restrict__ x,
    const float* __restrict__ gam, const float* __restrict__ bet, float* __restrict__ o)
{
    int row = blockIdx.x;
    int tid = threadIdx.x;
    float4 v = ((const float4*)(x + (size_t)row*DD))[tid];
    float s  = v.x+v.y+v.z+v.w;
    float ss = v.x*v.x+v.y*v.y+v.z*v.z+v.w*v.w;
    __shared__ float r1[256], r2[256];
    r1[tid]=s; r2[tid]=ss;
    __syncthreads();
    for (int off=128; off>0; off>>=1){
        if (tid<off){ r1[tid]+=r1[tid+off]; r2[tid]+=r2[tid+off]; }
        __syncthreads();
    }
    float mean = r1[0] * (1.f/DD);
    float var  = r2[0] * (1.f/DD) - mean*mean;
    float inv  = 1.f / sqrtf(var + 1e-5f);
    float4 g = ((const float4*)gam)[tid];
    float4 b = ((const float4*)bet)[tid];
    float4 r;
    r.x = (v.x-mean)*inv*g.x + b.x;
    r.y = (v.y-mean)*inv*g.y + b.y;
    r.z = (v.z-mean)*inv*g.z + b.z;
    r.w = (v.w-mean)*inv*g.w + b.w;
    ((float4*)(o + (size_t)row*DD))[tid] = r;
}

// ---------------- Generic f32 GEMM: C[M,N] = op(A[M,K] @ W[K,N] + bias) ------
// GATHER: A row index comes from gmap (negative -> zero row).
// Expert weights: e = m0 / rowsPerExp; W += e*wStride, bias += e*bStride.
// Epilogue: v=(acc+bias)*scale; if(res) v+=res[m,n]; if(RELU) v=max(v,0).
template<bool GATHER, bool RELU>
__global__ __launch_bounds__(256) void gemm_f32(
    const float* __restrict__ A, const float* __restrict__ W,
    const float* __restrict__ bias, const float* __restrict__ res,
    const int* __restrict__ gmap, float* __restrict__ C,
    int M, int N, int K, float scale, long wStride, int bStride, int rowsPerExp)
{
    __shared__ float As[64][20];   // stride 20: float4-aligned, 2-way bank max
    __shared__ float Ws[16][64];
    int tid = threadIdx.x;
    int m0 = blockIdx.y*64, n0 = blockIdx.x*64;
    int e = m0 / rowsPerExp;
    const float* Wp = W + (size_t)e*wStride;
    const float* bp = bias + (size_t)e*bStride;
    int lr = tid>>2, lk = (tid&3)<<2;     // A tile load: row lr, k-offset lk
    int wk = tid>>4, wn = (tid&15)<<2;    // W tile load
    int tm = (tid>>4)<<2, tn = (tid&15)<<2; // 4x4 microtile
    int arow = m0 + lr;
    int ga = GATHER ? gmap[arow] : arow;
    const float* Abase = (ga>=0) ? (A + (size_t)ga*K) : nullptr;
    float acc[4][4] = {};
    for (int k0=0; k0<K; k0+=16){
        float4 av = Abase ? *((const float4*)(Abase + k0 + lk))
                          : make_float4(0.f,0.f,0.f,0.f);
        *((float4*)&As[lr][lk]) = av;
        *((float4*)&Ws[wk][wn]) = *((const float4*)(Wp + (size_t)(k0+wk)*N + n0 + wn));
        __syncthreads();
        #pragma unroll
        for (int kk=0;kk<16;kk++){
            float a0=As[tm+0][kk], a1=As[tm+1][kk], a2=As[tm+2][kk], a3=As[tm+3][kk];
            float4 bv = *((float4*)&Ws[kk][tn]);
            acc[0][0]+=a0*bv.x; acc[0][1]+=a0*bv.y; acc[0][2]+=a0*bv.z; acc[0][3]+=a0*bv.w;
            acc[1][0]+=a1*bv.x; acc[1][1]+=a1*bv.y; acc[1][2]+=a1*bv.z; acc[1][3]+=a1*bv.w;
            acc[2][0]+=a2*bv.x; acc[2][1]+=a2*bv.y; acc[2][2]+=a2*bv.z; acc[2][3]+=a2*bv.w;
            acc[3][0]+=a3*bv.x; acc[3][1]+=a3*bv.y; acc[3][2]+=a3*bv.z; acc[3][3]+=a3*bv.w;
        }
        __syncthreads();
    }
    float4 bv = *((const float4*)(bp + n0 + tn));
    #pragma unroll
    for (int i=0;i<4;i++){
        int m = m0 + tm + i;
        float4 o;
        o.x = (acc[i][0]+bv.x)*scale;
        o.y = (acc[i][1]+bv.y)*scale;
        o.z = (acc[i][2]+bv.z)*scale;
        o.w = (acc[i][3]+bv.w)*scale;
        if (res){
            float4 rv = *((const float4*)(res + (size_t)m*N + n0 + tn));
            o.x+=rv.x; o.y+=rv.y; o.z+=rv.z; o.w+=rv.w;
        }
        if (RELU){
            o.x=fmaxf(o.x,0.f); o.y=fmaxf(o.y,0.f); o.z=fmaxf(o.z,0.f); o.w=fmaxf(o.w,0.f);
        }
        *((float4*)(C + (size_t)m*N + n0 + tn)) = o;
    }
}

// ---------------- Flash-style f32 attention ---------------------------------
// Grid: (T/64, B*H). Block 256 = 64 q-rows, online softmax over all 2048 keys.
// P-tile reuses the K-tile LDS to stay under 64KB static LDS.
__global__ __launch_bounds__(256) void attn_kernel(const float* __restrict__ q,
    const float* __restrict__ k, const float* __restrict__ v, float* __restrict__ o)
{
    int t0 = blockIdx.x * 64;
    int b  = blockIdx.y / HH;
    int h  = blockIdx.y % HH;
    __shared__ float Qs[64][65], Ks[64][65], Vs[64][65];
    __shared__ float m_row[64], l_row[64], c_row[64];
    int tid = threadIdx.x;
    int tm = (tid>>4)<<2, tn = (tid&15)<<2;
    #pragma unroll
    for (int i=0;i<4;i++){
        int idx = tid + 256*i;
        int r = idx>>4, c4 = (idx&15)<<2;
        float4 qv = *((const float4*)(q + ((size_t)(t0+r)*BB + b)*DD + h*HD + c4));
        Qs[r][c4+0]=qv.x; Qs[r][c4+1]=qv.y; Qs[r][c4+2]=qv.z; Qs[r][c4+3]=qv.w;
    }
    if (tid<64){ m_row[tid] = -3.0e38f; l_row[tid]=0.f; }
    float acc[4][4] = {};
    for (int s0=0; s0<TT; s0+=64){
        __syncthreads();   // prior PV reads of Ks/Vs done
        #pragma unroll
        for (int i=0;i<4;i++){
            int idx = tid + 256*i;
            int r = idx>>4, c4 = (idx&15)<<2;
            size_t gofs = ((size_t)(s0+r)*BB + b)*DD + h*HD + c4;
            float4 kv = *((const float4*)(k + gofs));
            float4 vv = *((const float4*)(v + gofs));
            Ks[r][c4+0]=kv.x; Ks[r][c4+1]=kv.y; Ks[r][c4+2]=kv.z; Ks[r][c4+3]=kv.w;
            Vs[r][c4+0]=vv.x; Vs[r][c4+1]=vv.y; Vs[r][c4+2]=vv.z; Vs[r][c4+3]=vv.w;
        }
        __syncthreads();
        float sacc[4][4] = {};
        for (int d=0; d<64; d++){
            float a0=Qs[tm+0][d], a1=Qs[tm+1][d], a2=Qs[tm+2][d], a3=Qs[tm+3][d];
            float b0=Ks[tn+0][d], b1=Ks[tn+1][d], b2=Ks[tn+2][d], b3=Ks[tn+3][d];
            sacc[0][0]+=a0*b0; sacc[0][1]+=a0*b1; sacc[0][2]+=a0*b2; sacc[0][3]+=a0*b3;
            sacc[1][0]+=a1*b0; sacc[1][1]+=a1*b1; sacc[1][2]+=a1*b2; sacc[1][3]+=a1*b3;
            sacc[2][0]+=a2*b0; sacc[2][1]+=a2*b1; sacc[2][2]+=a2*b2; sacc[2][3]+=a2*b3;
            sacc[3][0]+=a3*b0; sacc[3][1]+=a3*b1; sacc[3][2]+=a3*b2; sacc[3][3]+=a3*b3;
        }
        __syncthreads();   // everyone done READING Ks; reuse it as P
        #pragma unroll
        for (int i=0;i<4;i++)
            #pragma unroll
            for (int j=0;j<4;j++)
                Ks[tm+i][tn+j] = sacc[i][j];
        __syncthreads();
        if (tid<64){
            int r = tid;
            float mx = -3.0e38f;
            for (int s2=0;s2<64;s2++) mx = fmaxf(mx, Ks[r][s2]);
            float nm = fmaxf(m_row[r], mx);
            float corr = __expf(m_row[r] - nm);
            float ts = 0.f;
            for (int s2=0;s2<64;s2++){ float p=__expf(Ks[r][s2]-nm); Ks[r][s2]=p; ts+=p; }
            l_row[r] = l_row[r]*corr + ts;
            c_row[r] = corr; m_row[r] = nm;
        }
        __syncthreads();
        float cr0=c_row[tm+0], cr1=c_row[tm+1], cr2=c_row[tm+2], cr3=c_row[tm+3];
        #pragma unroll
        for (int j=0;j<4;j++){ acc[0][j]*=cr0; acc[1][j]*=cr1; acc[2][j]*=cr2; acc[3][j]*=cr3; }
        for (int s2=0;s2<64;s2++){
            float p0=Ks[tm+0][s2], p1=Ks[tm+1][s2], p2=Ks[tm+2][s2], p3=Ks[tm+3][s2];
            float v0=Vs[s2][tn+0], v1=Vs[s2][tn+1], v2=Vs[s2][tn+2], v3=Vs[s2][tn+3];
            acc[0][0]+=p0*v0; acc[0][1]+=p0*v1; acc[0][2]+=p0*v2; acc[0][3]+=p0*v3;
            acc[1][0]+=p1*v0; acc[1][1]+=p1*v1; acc[1][2]+=p1*v2; acc[1][3]+=p1*v3;
            acc[2][0]+=p2*v0; acc[2][1]+=p2*v1; acc[2][2]+=p2*v2; acc[2][3]+=p2*v3;
            acc[3][0]+=p3*v0; acc[3][1]+=p3*v1; acc[3][2]+=p3*v2; acc[3][3]+=p3*v3;
        }
    }
    #pragma unroll
    for (int i=0;i<4;i++){
        float il = 1.f/l_row[tm+i];
        float4 ov = make_float4(acc[i][0]*il, acc[i][1]*il, acc[i][2]*il, acc[i][3]*il);
        *((float4*)(o + ((size_t)(t0+tm+i)*BB + b)*DD + h*HD + tn)) = ov;
    }
}

// ---------------- Routing: logits -> softmax, top1/top2 (first-index ties) ---
// One wave per token (batch-major token s: b=s/T, t=s%T, h2 row = t*B+b).
__global__ __launch_bounds__(256) void route_kernel(const float* __restrict__ h2,
    const float* __restrict__ wgm, float* __restrict__ gates,
    int* __restrict__ idx1, int* __restrict__ idx2,
    float* __restrict__ g1, float* __restrict__ g2)
{
    int wid = threadIdx.x >> 6, lane = threadIdx.x & 63;
    int s = blockIdx.x*4 + wid;
    int row = (s % TT)*BB + (s / TT);
    const float* hr = h2 + (size_t)row*DD;
    float acc[EE] = {};
    #pragma unroll
    for (int c=0;c<16;c++){
        int d = c*64 + lane;
        float xv = hr[d];
        const float* wr = wgm + (size_t)d*EE;
        #pragma unroll
        for (int e2=0;e2<EE;e2++) acc[e2] += xv * wr[e2];
    }
    #pragma unroll
    for (int off=32; off>0; off>>=1){
        #pragma unroll
        for (int e2=0;e2<EE;e2++) acc[e2] += __shfl_down(acc[e2], off);
    }
    if (lane==0){
        float mx = acc[0];
        #pragma unroll
        for (int e2=1;e2<EE;e2++) mx = fmaxf(mx, acc[e2]);
        float ex[EE]; float sum=0.f;
        #pragma unroll
        for (int e2=0;e2<EE;e2++){ ex[e2] = __expf(acc[e2]-mx); sum += ex[e2]; }
        float inv = 1.f/sum;
        int i1=0; float bv1=acc[0];
        #pragma unroll
        for (int e2=1;e2<EE;e2++){ if (acc[e2] > bv1){ bv1=acc[e2]; i1=e2; } }
        int i2=-1; float bv2=-3.0e38f;
        #pragma unroll
        for (int e2=0;e2<EE;e2++){ if (e2!=i1 && acc[e2] > bv2){ bv2=acc[e2]; i2=e2; } }
        #pragma unroll
        for (int e2=0;e2<EE;e2++) gates[(size_t)s*EE + e2] = ex[e2]*inv;
        idx1[s]=i1; idx2[s]=i2;
        g1[s]=ex[i1]*inv; g2[s]=ex[i2]*inv;
    }
}

// ---------------- Single-block deterministic scan (positions, caps, l_aux) ---
__global__ __launch_bounds__(256) void scan_kernel(
    const float* __restrict__ gates, const int* __restrict__ idx1, const int* __restrict__ idx2,
    const float* __restrict__ g1, const float* __restrict__ g2,
    float* __restrict__ g1n, float* __restrict__ g2n,
    int* __restrict__ f1, int* __restrict__ f2, int* __restrict__ slot2row,
    float* __restrict__ laux)
{
    __shared__ int i1s[SS];
    __shared__ int i2s[SS];
    __shared__ int cnt1[256][EE];
    __shared__ int cnt2[256][EE];
    __shared__ float gsum[256][EE];
    __shared__ int tot1[EE];
    int tid = threadIdx.x;
    for (int i=tid;i<EE*CAP;i+=256) slot2row[i] = -1;
    for (int i=tid;i<SS;i+=256){ i1s[i]=idx1[i]; i2s[i]=idx2[i]; }
    __syncthreads();
    int c1l[EE]={}, c2l[EE]={};
    float gl[EE]={};
    int base = tid*16;
    for (int qq=0;qq<16;qq++){
        int s = base+qq;
        c1l[i1s[s]]++; c2l[i2s[s]]++;
        #pragma unroll
        for (int e2=0;e2<EE;e2++) gl[e2] += gates[(size_t)s*EE+e2];
    }
    #pragma unroll
    for (int e2=0;e2<EE;e2++){ cnt1[tid][e2]=c1l[e2]; cnt2[tid][e2]=c2l[e2]; gsum[tid][e2]=gl[e2]; }
    __syncthreads();
    if (tid < EE){
        int e2 = tid;
        int run=0;
        for (int t=0;t<256;t++){ int tmp=cnt1[t][e2]; cnt1[t][e2]=run; run+=tmp; }
        tot1[e2]=run;
        run=0;
        for (int t=0;t<256;t++){ int tmp=cnt2[t][e2]; cnt2[t][e2]=run; run+=tmp; }
        float gr=0.f;
        for (int t=0;t<256;t++) gr += gsum[t][e2];
        gsum[0][e2]=gr;
    }
    __syncthreads();
    int p1[EE], p2[EE];
    #pragma unroll
    for (int e2=0;e2<EE;e2++){ p1[e2]=cnt1[tid][e2]; p2[e2]=cnt2[tid][e2]+tot1[e2]; }
    for (int qq=0;qq<16;qq++){
        int s = base+qq;
        int e1 = i1s[s], e2v = i2s[s];
        int pos1 = p1[e1]++;
        int pos2 = p2[e2v]++;
        float gv1 = g1[s], gv2 = g2[s];
        float gm1 = (pos1<CAP)? gv1 : 0.f;
        float gm2 = (pos2<CAP)? gv2 : 0.f;
        float den = fmaxf(gm1+gm2, EPSF);
        g1n[s] = gm1/den; g2n[s] = gm2/den;
        int ff1 = e1*CAP + (pos1<CAP?pos1:CAP-1);
        int ff2 = e2v*CAP + (pos2<CAP?pos2:CAP-1);
        f1[s]=ff1; f2[s]=ff2;
        int hrow = (s % TT)*BB + (s / TT);
        if (pos1<CAP) slot2row[ff1]=hrow;
        if (pos2<CAP) slot2row[ff2]=hrow;
    }
    if (tid==0){
        float a=0.f;
        #pragma unroll
        for (int e2=0;e2<EE;e2++) a += (gsum[0][e2]*(1.f/SS)) * ((float)tot1[e2]*(1.f/SS));
        laux[0] = a * (float)EE;   // == E*E * mean_e(...) with mean = sum/E
    }
}

// ---------------- Combine: out[t,b,:] = x2 + g1n*eout[f1] + g2n*eout[f2] -----
__global__ __launch_bounds__(256) void combine_kernel(const float* __restrict__ x2,
    const float* __restrict__ eout, const float* __restrict__ g1n, const float* __restrict__ g2n,
    const int* __restrict__ f1, const int* __restrict__ f2, float* __restrict__ out)
{
    int s = blockIdx.x;
    float a = g1n[s], b = g2n[s];
    int s1 = f1[s], s2 = f2[s];
    int row = (s % TT)*BB + (s / TT);
    int c = threadIdx.x;
    float4 o1 = ((const float4*)(eout + (size_t)s1*DD))[c];
    float4 o2 = ((const float4*)(eout + (size_t)s2*DD))[c];
    float4 xr = ((const float4*)(x2 + (size_t)row*DD))[c];
    float4 r;
    r.x = xr.x + a*o1.x + b*o2.x;
    r.y = xr.y + a*o1.y + b*o2.y;
    r.z = xr.z + a*o1.z + b*o2.z;
    r.w = xr.w + a*o1.w + b*o2.w;
    ((float4*)(out + (size_t)row*DD))[c] = r;
}

extern "C" void kernel_launch(void* const* d_in, const int* in_sizes, int n_in,
                              void* d_out, int out_size, void* d_ws, size_t ws_size,
                              hipStream_t stream)
{
    const float* x    = (const float*)d_in[0];
    const float* Wq   = (const float*)d_in[1];
    const float* bq   = (const float*)d_in[2];
    const float* Wk   = (const float*)d_in[3];
    const float* bk   = (const float*)d_in[4];
    const float* Wv   = (const float*)d_in[5];
    const float* bv   = (const float*)d_in[6];
    const float* Wo   = (const float*)d_in[7];
    const float* bo   = (const float*)d_in[8];
    const float* ln1g = (const float*)d_in[9];
    const float* ln1b = (const float*)d_in[10];
    const float* ln2g = (const float*)d_in[11];
    const float* ln2b = (const float*)d_in[12];
    const float* wgm  = (const float*)d_in[13];
    const float* W1   = (const float*)d_in[14];
    const float* b1   = (const float*)d_in[15];
    const float* W2   = (const float*)d_in[16];
    const float* b2   = (const float*)d_in[17];
    float* out = (float*)d_out;

    char* w = (char*)d_ws;
    float* h1   = (float*)(w);                       // 16MB; later attn_o
    float* qb   = (float*)(w + ((size_t)16<<20));    // 16MB; later h2
    float* kb   = (float*)(w + ((size_t)32<<20));    // 16MB
    float* vb   = (float*)(w + ((size_t)48<<20));    // 16MB
    float* x2   = (float*)(w + ((size_t)64<<20));    // 16MB
    float* ffnh = (float*)(w + ((size_t)80<<20));    // 128MB
    float* ffno = (float*)(w + ((size_t)208<<20));   // 32MB
    char*  sm   = w + ((size_t)240<<20);
    float* gates   = (float*)(sm);                sm += (size_t)SS*EE*4;  // 128KB
    int*   idx1    = (int*)(sm);                  sm += SS*4;
    int*   idx2    = (int*)(sm);                  sm += SS*4;
    float* g1      = (float*)(sm);                sm += SS*4;
    float* g2      = (float*)(sm);                sm += SS*4;
    float* g1n     = (float*)(sm);                sm += SS*4;
    float* g2n     = (float*)(sm);                sm += SS*4;
    int*   f1      = (int*)(sm);                  sm += SS*4;
    int*   f2      = (int*)(sm);                  sm += SS*4;
    int*   slot2row= (int*)(sm);                  sm += EE*CAP*4;

    dim3 gProj(DD/64, SS/64);       // (16, 64)
    // 1. LN1
    ln_kernel<<<SS, 256, 0, stream>>>(x, ln1g, ln1b, h1);
    // 2-4. Q,K,V projections (q scaled by HD^-0.5)
    gemm_f32<false,false><<<gProj, 256, 0, stream>>>(h1, Wq, bq, nullptr, nullptr, qb,
        SS, DD, DD, 0.125f, 0, 0, 1<<30);
    gemm_f32<false,false><<<gProj, 256, 0, stream>>>(h1, Wk, bk, nullptr, nullptr, kb,
        SS, DD, DD, 1.0f, 0, 0, 1<<30);
    gemm_f32<false,false><<<gProj, 256, 0, stream>>>(h1, Wv, bv, nullptr, nullptr, vb,
        SS, DD, DD, 1.0f, 0, 0, 1<<30);
    // 5. attention -> h1 (reuse)
    attn_kernel<<<dim3(TT/64, BB*HH), 256, 0, stream>>>(qb, kb, vb, h1);
    // 6. O-projection + residual -> x2
    gemm_f32<false,false><<<gProj, 256, 0, stream>>>(h1, Wo, bo, x, nullptr, x2,
        SS, DD, DD, 1.0f, 0, 0, 1<<30);
    // 7. LN2 -> h2 (reuse qb)
    ln_kernel<<<SS, 256, 0, stream>>>(x2, ln2g, ln2b, qb);
    // 8. routing logits/gates/top2
    route_kernel<<<SS/4, 256, 0, stream>>>(qb, wgm, gates, idx1, idx2, g1, g2);
    // 9. deterministic scan: positions, capacity, slot map, l_aux -> out[S*D]
    scan_kernel<<<1, 256, 0, stream>>>(gates, idx1, idx2, g1, g2,
        g1n, g2n, f1, f2, slot2row, out + (size_t)SS*DD);
    // 10. expert GEMM1 (gathered A, relu): [8192,4096]
    gemm_f32<true,true><<<dim3(FF/64, (EE*CAP)/64), 256, 0, stream>>>(qb, W1, b1,
        nullptr, slot2row, ffnh, EE*CAP, FF, DD, 1.0f, (long)DD*FF, FF, CAP);
    // 11. expert GEMM2: [8192,1024]
    gemm_f32<false,false><<<dim3(DD/64, (EE*CAP)/64), 256, 0, stream>>>(ffnh, W2, b2,
        nullptr, nullptr, ffno, EE*CAP, DD, FF, 1.0f, (long)FF*DD, DD, CAP);
    // 12. combine + residual -> out
    combine_kernel<<<SS, 256, 0, stream>>>(x2, ffno, g1n, g2n, f1, f2, out);
    (void)in_sizes; (void)n_in; (void)out_size; (void)ws_size;
}

// Round 2
// 1595.835 us; speedup vs baseline: 2.1789x; 2.1789x over previous
//
#include <hip/hip_runtime.h>

#define TT 2048
#define BB 2
#define DD 1024
#define HH 16
#define HD 64
#define FF 4096
#define EE 8
#define SS (TT*BB)     // 4096 tokens
#define CAP 1024       // 2*ceil(S/E)
#define EPSF 1.1920929e-07f

typedef __attribute__((ext_vector_type(8))) short short8;
typedef __attribute__((ext_vector_type(4))) float floatx4;

static __device__ inline unsigned short f2bf(float f){
    unsigned int u = __float_as_uint(f);
    unsigned int r = (u + 0x7fffu + ((u>>16)&1u)) >> 16;
    return (unsigned short)r;
}

// ---------------- LayerNorm: one row (D=1024) per block, 256 thr x float4 ----
__global__ __launch_bounds__(256) void ln_kernel(const float* __restrict__ x,
    const float* __restrict__ gam, const float* __restrict__ bet, float* __restrict__ o)
{
    int row = blockIdx.x;
    int tid = threadIdx.x;
    float4 v = ((const float4*)(x + (size_t)row*DD))[tid];
    float s  = v.x+v.y+v.z+v.w;
    float ss = v.x*v.x+v.y*v.y+v.z*v.z+v.w*v.w;
    __shared__ float r1[256], r2[256];
    r1[tid]=s; r2[tid]=ss;
    __syncthreads();
    for (int off=128; off>0; off>>=1){
        if (tid<off){ r1[tid]+=r1[tid+off]; r2[tid]+=r2[tid+off]; }
        __syncthreads();
    }
    float mean = r1[0] * (1.f/DD);
    float var  = r2[0] * (1.f/DD) - mean*mean;
    float inv  = 1.f / sqrtf(var + 1e-5f);
    float4 g = ((const float4*)gam)[tid];
    float4 b = ((const float4*)bet)[tid];
    float4 r;
    r.x = (v.x-mean)*inv*g.x + b.x;
    r.y = (v.y-mean)*inv*g.y + b.y;
    r.z = (v.z-mean)*inv*g.z + b.z;
    r.w = (v.w-mean)*inv*g.w + b.w;
    ((float4*)(o + (size_t)row*DD))[tid] = r;
}

// ---------------- Generic f32 GEMM (QKV/O projections only) -----------------
template<bool GATHER, bool RELU>
__global__ __launch_bounds__(256) void gemm_f32(
    const float* __restrict__ A, const float* __restrict__ W,
    const float* __restrict__ bias, const float* __restrict__ res,
    const int* __restrict__ gmap, float* __restrict__ C,
    int M, int N, int K, float scale, long wStride, int bStride, int rowsPerExp)
{
    __shared__ float As[64][20];
    __shared__ float Ws[16][64];
    int tid = threadIdx.x;
    int m0 = blockIdx.y*64, n0 = blockIdx.x*64;
    int e = m0 / rowsPerExp;
    const float* Wp = W + (size_t)e*wStride;
    const float* bp = bias + (size_t)e*bStride;
    int lr = tid>>2, lk = (tid&3)<<2;
    int wk = tid>>4, wn = (tid&15)<<2;
    int tm = (tid>>4)<<2, tn = (tid&15)<<2;
    int arow = m0 + lr;
    int ga = GATHER ? gmap[arow] : arow;
    const float* Abase = (ga>=0) ? (A + (size_t)ga*K) : nullptr;
    float acc[4][4] = {};
    for (int k0=0; k0<K; k0+=16){
        float4 av = Abase ? *((const float4*)(Abase + k0 + lk))
                          : make_float4(0.f,0.f,0.f,0.f);
        *((float4*)&As[lr][lk]) = av;
        *((float4*)&Ws[wk][wn]) = *((const float4*)(Wp + (size_t)(k0+wk)*N + n0 + wn));
        __syncthreads();
        #pragma unroll
        for (int kk=0;kk<16;kk++){
            float a0=As[tm+0][kk], a1=As[tm+1][kk], a2=As[tm+2][kk], a3=As[tm+3][kk];
            float4 bv = *((float4*)&Ws[kk][tn]);
            acc[0][0]+=a0*bv.x; acc[0][1]+=a0*bv.y; acc[0][2]+=a0*bv.z; acc[0][3]+=a0*bv.w;
            acc[1][0]+=a1*bv.x; acc[1][1]+=a1*bv.y; acc[1][2]+=a1*bv.z; acc[1][3]+=a1*bv.w;
            acc[2][0]+=a2*bv.x; acc[2][1]+=a2*bv.y; acc[2][2]+=a2*bv.z; acc[2][3]+=a2*bv.w;
            acc[3][0]+=a3*bv.x; acc[3][1]+=a3*bv.y; acc[3][2]+=a3*bv.z; acc[3][3]+=a3*bv.w;
        }
        __syncthreads();
    }
    float4 bv = *((const float4*)(bp + n0 + tn));
    #pragma unroll
    for (int i=0;i<4;i++){
        int m = m0 + tm + i;
        float4 o;
        o.x = (acc[i][0]+bv.x)*scale;
        o.y = (acc[i][1]+bv.y)*scale;
        o.z = (acc[i][2]+bv.z)*scale;
        o.w = (acc[i][3]+bv.w)*scale;
        if (res){
            float4 rv = *((const float4*)(res + (size_t)m*N + n0 + tn));
            o.x+=rv.x; o.y+=rv.y; o.z+=rv.z; o.w+=rv.w;
        }
        if (RELU){
            o.x=fmaxf(o.x,0.f); o.y=fmaxf(o.y,0.f); o.z=fmaxf(o.z,0.f); o.w=fmaxf(o.w,0.f);
        }
        *((float4*)(C + (size_t)m*N + n0 + tn)) = o;
    }
}

// ---------------- bf16 MFMA GEMM: C[M,N] = op(A[M,K] @ Bt[N,K]^T + bias) ----
// A: bf16 [M,K] row-major. Bt: bf16 [E][N][K] (K-contiguous). 128x128 tile,
// BK=64, 4 waves (2x2), 4x4 16x16x32 fragments/wave, XOR-swizzled LDS.
template<bool RELU, bool OUTBF16>
__global__ __launch_bounds__(256) void gemm_mfma(
    const unsigned short* __restrict__ A, const unsigned short* __restrict__ Bt,
    const float* __restrict__ bias, float* __restrict__ Cf,
    unsigned short* __restrict__ Cb,
    int M, int N, int K, long wStride, int bStride, int rowsPerExp)
{
    __shared__ unsigned short As[128*64];
    __shared__ unsigned short Bs[128*64];
    const int tid = threadIdx.x, lane = tid&63;
    const int w = tid>>6, wr = w>>1, wc = w&1;
    const int m0 = blockIdx.y*128, n0 = blockIdx.x*128;
    const int e = m0 / rowsPerExp;
    const unsigned short* Bp = Bt + (size_t)e*wStride;
    const int srow = tid>>3, sslot = tid&7;   // staging: rows srow+32i, 16B chunk sslot
    floatx4 zf = {0.f,0.f,0.f,0.f};
    floatx4 acc[4][4];
    #pragma unroll
    for (int m=0;m<4;m++)
        #pragma unroll
        for (int n=0;n<4;n++) acc[m][n]=zf;

    short8 ar[4], br[4];
    #pragma unroll
    for (int i=0;i<4;i++){
        int r = srow + i*32;
        ar[i] = *(const short8*)(A  + (size_t)(m0+r)*K + sslot*8);
        br[i] = *(const short8*)(Bp + (size_t)(n0+r)*K + sslot*8);
    }
    const int NT = K/64;
    for (int kt=0; kt<NT; kt++){
        __syncthreads();
        #pragma unroll
        for (int i=0;i<4;i++){
            int r = srow + i*32;
            int off = r*64 + ((sslot ^ (r&7))<<3);   // swizzled 8-elem group
            *(short8*)(&As[off]) = ar[i];
            *(short8*)(&Bs[off]) = br[i];
        }
        __syncthreads();
        if (kt+1 < NT){
            int k0 = (kt+1)*64;
            #pragma unroll
            for (int i=0;i<4;i++){
                int r = srow + i*32;
                ar[i] = *(const short8*)(A  + (size_t)(m0+r)*K + k0 + sslot*8);
                br[i] = *(const short8*)(Bp + (size_t)(n0+r)*K + k0 + sslot*8);
            }
        }
        #pragma unroll
        for (int kk=0;kk<2;kk++){
            short8 af[4], bf[4];
            int kgrp = kk*4 + (lane>>4);        // 8-elem k-group index 0..7
            #pragma unroll
            for (int m=0;m<4;m++){
                int rowa = wr*64 + m*16 + (lane&15);
                af[m] = *(const short8*)(&As[rowa*64 + ((kgrp ^ (rowa&7))<<3)]);
                int rowb = wc*64 + m*16 + (lane&15);
                bf[m] = *(const short8*)(&Bs[rowb*64 + ((kgrp ^ (rowb&7))<<3)]);
            }
            #pragma unroll
            for (int m=0;m<4;m++)
                #pragma unroll
                for (int n=0;n<4;n++)
                    acc[m][n] = __builtin_amdgcn_mfma_f32_16x16x32_bf16(af[m], bf[n], acc[m][n], 0,0,0);
        }
    }
    // epilogue: D[row=(l>>4)*4+i][col=l&15] per fragment (m89 layout)
    int colg = n0 + wc*64 + (lane&15);
    int rowg = m0 + wr*64 + ((lane>>4)<<2);
    #pragma unroll
    for (int n=0;n<4;n++){
        float bv = bias[e*bStride + colg + n*16];
        #pragma unroll
        for (int m=0;m<4;m++){
            #pragma unroll
            for (int i2=0;i2<4;i2++){
                float v = acc[m][n][i2] + bv;
                if (RELU) v = fmaxf(v, 0.f);
                size_t o = (size_t)(rowg + m*16 + i2)*N + colg + n*16;
                if (OUTBF16) Cb[o] = f2bf(v); else Cf[o] = v;
            }
        }
    }
}

// ---------------- transpose+convert: in [E][R][C] f32 -> out [E][C][R] bf16 --
__global__ __launch_bounds__(256) void transpose_bf16_k(const float* __restrict__ in,
    unsigned short* __restrict__ outp, int R, int C)
{
    __shared__ float t[64][65];
    int e = blockIdx.z;
    const float* ip = in + (size_t)e*R*C;
    unsigned short* op = outp + (size_t)e*R*C;
    int r0 = blockIdx.y*64, c0 = blockIdx.x*64;
    int tid = threadIdx.x;
    #pragma unroll
    for (int i=0;i<4;i++){
        int ch = i*256 + tid;
        int r = ch>>4, c4 = (ch&15)*4;
        float4 v = *(const float4*)(ip + (size_t)(r0+r)*C + c0 + c4);
        t[r][c4+0]=v.x; t[r][c4+1]=v.y; t[r][c4+2]=v.z; t[r][c4+3]=v.w;
    }
    __syncthreads();
    #pragma unroll
    for (int i=0;i<4;i++){
        int ch = i*256 + tid;
        int rr = ch>>4, c4 = (ch&15)*4;
        ushort4 o;
        o.x = f2bf(t[c4+0][rr]); o.y = f2bf(t[c4+1][rr]);
        o.z = f2bf(t[c4+2][rr]); o.w = f2bf(t[c4+3][rr]);
        *(ushort4*)(op + (size_t)(c0+rr)*R + r0 + c4) = o;
    }
}

// ---------------- gather dispatch buffer: buf[s] = bf16(h2[slot2row[s]]) -----
__global__ __launch_bounds__(256) void gather_bf16_k(const float* __restrict__ h2,
    const int* __restrict__ s2r, unsigned short* __restrict__ buf)
{
    int s = blockIdx.x; int row = s2r[s]; int c = threadIdx.x;
    float4 v = make_float4(0.f,0.f,0.f,0.f);
    if (row>=0) v = *(const float4*)(h2 + (size_t)row*DD + c*4);
    ushort4 o;
    o.x=f2bf(v.x); o.y=f2bf(v.y); o.z=f2bf(v.z); o.w=f2bf(v.w);
    *(ushort4*)(buf + (size_t)s*DD + c*4) = o;
}

// ---------------- Flash-style f32 attention (unchanged, routing-critical) ---
__global__ __launch_bounds__(256) void attn_kernel(const float* __restrict__ q,
    const float* __restrict__ k, const float* __restrict__ v, float* __restrict__ o)
{
    int t0 = blockIdx.x * 64;
    int b  = blockIdx.y / HH;
    int h  = blockIdx.y % HH;
    __shared__ float Qs[64][65], Ks[64][65], Vs[64][65];
    __shared__ float m_row[64], l_row[64], c_row[64];
    int tid = threadIdx.x;
    int tm = (tid>>4)<<2, tn = (tid&15)<<2;
    #pragma unroll
    for (int i=0;i<4;i++){
        int idx = tid + 256*i;
        int r = idx>>4, c4 = (idx&15)<<2;
        float4 qv = *((const float4*)(q + ((size_t)(t0+r)*BB + b)*DD + h*HD + c4));
        Qs[r][c4+0]=qv.x; Qs[r][c4+1]=qv.y; Qs[r][c4+2]=qv.z; Qs[r][c4+3]=qv.w;
    }
    if (tid<64){ m_row[tid] = -3.0e38f; l_row[tid]=0.f; }
    float acc[4][4] = {};
    for (int s0=0; s0<TT; s0+=64){
        __syncthreads();
        #pragma unroll
        for (int i=0;i<4;i++){
            int idx = tid + 256*i;
            int r = idx>>4, c4 = (idx&15)<<2;
            size_t gofs = ((size_t)(s0+r)*BB + b)*DD + h*HD + c4;
            float4 kv = *((const float4*)(k + gofs));
            float4 vv = *((const float4*)(v + gofs));
            Ks[r][c4+0]=kv.x; Ks[r][c4+1]=kv.y; Ks[r][c4+2]=kv.z; Ks[r][c4+3]=kv.w;
            Vs[r][c4+0]=vv.x; Vs[r][c4+1]=vv.y; Vs[r][c4+2]=vv.z; Vs[r][c4+3]=vv.w;
        }
        __syncthreads();
        float sacc[4][4] = {};
        for (int d=0; d<64; d++){
            float a0=Qs[tm+0][d], a1=Qs[tm+1][d], a2=Qs[tm+2][d], a3=Qs[tm+3][d];
            float b0=Ks[tn+0][d], b1=Ks[tn+1][d], b2=Ks[tn+2][d], b3=Ks[tn+3][d];
            sacc[0][0]+=a0*b0; sacc[0][1]+=a0*b1; sacc[0][2]+=a0*b2; sacc[0][3]+=a0*b3;
            sacc[1][0]+=a1*b0; sacc[1][1]+=a1*b1; sacc[1][2]+=a1*b2; sacc[1][3]+=a1*b3;
            sacc[2][0]+=a2*b0; sacc[2][1]+=a2*b1; sacc[2][2]+=a2*b2; sacc[2][3]+=a2*b3;
            sacc[3][0]+=a3*b0; sacc[3][1]+=a3*b1; sacc[3][2]+=a3*b2; sacc[3][3]+=a3*b3;
        }
        __syncthreads();
        #pragma unroll
        for (int i=0;i<4;i++)
            #pragma unroll
            for (int j=0;j<4;j++)
                Ks[tm+i][tn+j] = sacc[i][j];
        __syncthreads();
        if (tid<64){
            int r = tid;
            float mx = -3.0e38f;
            for (int s2=0;s2<64;s2++) mx = fmaxf(mx, Ks[r][s2]);
            float nm = fmaxf(m_row[r], mx);
            float corr = __expf(m_row[r] - nm);
            float ts = 0.f;
            for (int s2=0;s2<64;s2++){ float p=__expf(Ks[r][s2]-nm); Ks[r][s2]=p; ts+=p; }
            l_row[r] = l_row[r]*corr + ts;
            c_row[r] = corr; m_row[r] = nm;
        }
        __syncthreads();
        float cr0=c_row[tm+0], cr1=c_row[tm+1], cr2=c_row[tm+2], cr3=c_row[tm+3];
        #pragma unroll
        for (int j=0;j<4;j++){ acc[0][j]*=cr0; acc[1][j]*=cr1; acc[2][j]*=cr2; acc[3][j]*=cr3; }
        for (int s2=0;s2<64;s2++){
            float p0=Ks[tm+0][s2], p1=Ks[tm+1][s2], p2=Ks[tm+2][s2], p3=Ks[tm+3][s2];
            float v0=Vs[s2][tn+0], v1=Vs[s2][tn+1], v2=Vs[s2][tn+2], v3=Vs[s2][tn+3];
            acc[0][0]+=p0*v0; acc[0][1]+=p0*v1; acc[0][2]+=p0*v2; acc[0][3]+=p0*v3;
            acc[1][0]+=p1*v0; acc[1][1]+=p1*v1; acc[1][2]+=p1*v2; acc[1][3]+=p1*v3;
            acc[2][0]+=p2*v0; acc[2][1]+=p2*v1; acc[2][2]+=p2*v2; acc[2][3]+=p2*v3;
            acc[3][0]+=p3*v0; acc[3][1]+=p3*v1; acc[3][2]+=p3*v2; acc[3][3]+=p3*v3;
        }
    }
    #pragma unroll
    for (int i=0;i<4;i++){
        float il = 1.f/l_row[tm+i];
        float4 ov = make_float4(acc[i][0]*il, acc[i][1]*il, acc[i][2]*il, acc[i][3]*il);
        *((float4*)(o + ((size_t)(t0+tm+i)*BB + b)*DD + h*HD + tn)) = ov;
    }
}

// ---------------- Routing (unchanged) ----------------------------------------
__global__ __launch_bounds__(256) void route_kernel(const float* __restrict__ h2,
    const float* __restrict__ wgm, float* __restrict__ gates,
    int* __restrict__ idx1, int* __restrict__ idx2,
    float* __restrict__ g1, float* __restrict__ g2)
{
    int wid = threadIdx.x >> 6, lane = threadIdx.x & 63;
    int s = blockIdx.x*4 + wid;
    int row = (s % TT)*BB + (s / TT);
    const float* hr = h2 + (size_t)row*DD;
    float acc[EE] = {};
    #pragma unroll
    for (int c=0;c<16;c++){
        int d = c*64 + lane;
        float xv = hr[d];
        const float* wr = wgm + (size_t)d*EE;
        #pragma unroll
        for (int e2=0;e2<EE;e2++) acc[e2] += xv * wr[e2];
    }
    #pragma unroll
    for (int off=32; off>0; off>>=1){
        #pragma unroll
        for (int e2=0;e2<EE;e2++) acc[e2] += __shfl_down(acc[e2], off);
    }
    if (lane==0){
        float mx = acc[0];
        #pragma unroll
        for (int e2=1;e2<EE;e2++) mx = fmaxf(mx, acc[e2]);
        float ex[EE]; float sum=0.f;
        #pragma unroll
        for (int e2=0;e2<EE;e2++){ ex[e2] = __expf(acc[e2]-mx); sum += ex[e2]; }
        float inv = 1.f/sum;
        int i1=0; float bv1=acc[0];
        #pragma unroll
        for (int e2=1;e2<EE;e2++){ if (acc[e2] > bv1){ bv1=acc[e2]; i1=e2; } }
        int i2=-1; float bv2=-3.0e38f;
        #pragma unroll
        for (int e2=0;e2<EE;e2++){ if (e2!=i1 && acc[e2] > bv2){ bv2=acc[e2]; i2=e2; } }
        #pragma unroll
        for (int e2=0;e2<EE;e2++) gates[(size_t)s*EE + e2] = ex[e2]*inv;
        idx1[s]=i1; idx2[s]=i2;
        g1[s]=ex[i1]*inv; g2[s]=ex[i2]*inv;
    }
}

// ---------------- Single-block deterministic scan (unchanged) ----------------
__global__ __launch_bounds__(256) void scan_kernel(
    const float* __restrict__ gates, const int* __restrict__ idx1, const int* __restrict__ idx2,
    const float* __restrict__ g1, const float* __restrict__ g2,
    float* __restrict__ g1n, float* __restrict__ g2n,
    int* __restrict__ f1, int* __restrict__ f2, int* __restrict__ slot2row,
    float* __restrict__ laux)
{
    __shared__ int i1s[SS];
    __shared__ int i2s[SS];
    __shared__ int cnt1[256][EE];
    __shared__ int cnt2[256][EE];
    __shared__ float gsum[256][EE];
    __shared__ int tot1[EE];
    int tid = threadIdx.x;
    for (int i=tid;i<EE*CAP;i+=256) slot2row[i] = -1;
    for (int i=tid;i<SS;i+=256){ i1s[i]=idx1[i]; i2s[i]=idx2[i]; }
    __syncthreads();
    int c1l[EE]={}, c2l[EE]={};
    float gl[EE]={};
    int base = tid*16;
    for (int qq=0;qq<16;qq++){
        int s = base+qq;
        c1l[i1s[s]]++; c2l[i2s[s]]++;
        #pragma unroll
        for (int e2=0;e2<EE;e2++) gl[e2] += gates[(size_t)s*EE+e2];
    }
    #pragma unroll
    for (int e2=0;e2<EE;e2++){ cnt1[tid][e2]=c1l[e2]; cnt2[tid][e2]=c2l[e2]; gsum[tid][e2]=gl[e2]; }
    __syncthreads();
    if (tid < EE){
        int e2 = tid;
        int run=0;
        for (int t=0;t<256;t++){ int tmp=cnt1[t][e2]; cnt1[t][e2]=run; run+=tmp; }
        tot1[e2]=run;
        run=0;
        for (int t=0;t<256;t++){ int tmp=cnt2[t][e2]; cnt2[t][e2]=run; run+=tmp; }
        float gr=0.f;
        for (int t=0;t<256;t++) gr += gsum[t][e2];
        gsum[0][e2]=gr;
    }
    __syncthreads();
    int p1[EE], p2[EE];
    #pragma unroll
    for (int e2=0;e2<EE;e2++){ p1[e2]=cnt1[tid][e2]; p2[e2]=cnt2[tid][e2]+tot1[e2]; }
    for (int qq=0;qq<16;qq++){
        int s = base+qq;
        int e1 = i1s[s], e2v = i2s[s];
        int pos1 = p1[e1]++;
        int pos2 = p2[e2v]++;
        float gv1 = g1[s], gv2 = g2[s];
        float gm1 = (pos1<CAP)? gv1 : 0.f;
        float gm2 = (pos2<CAP)? gv2 : 0.f;
        float den = fmaxf(gm1+gm2, EPSF);
        g1n[s] = gm1/den; g2n[s] = gm2/den;
        int ff1 = e1*CAP + (pos1<CAP?pos1:CAP-1);
        int ff2 = e2v*CAP + (pos2<CAP?pos2:CAP-1);
        f1[s]=ff1; f2[s]=ff2;
        int hrow = (s % TT)*BB + (s / TT);
        if (pos1<CAP) slot2row[ff1]=hrow;
        if (pos2<CAP) slot2row[ff2]=hrow;
    }
    if (tid==0){
        float a=0.f;
        #pragma unroll
        for (int e2=0;e2<EE;e2++) a += (gsum[0][e2]*(1.f/SS)) * ((float)tot1[e2]*(1.f/SS));
        laux[0] = a * (float)EE;
    }
}

// ---------------- Combine (unchanged) ----------------------------------------
__global__ __launch_bounds__(256) void combine_kernel(const float* __restrict__ x2,
    const float* __restrict__ eout, const float* __restrict__ g1n, const float* __restrict__ g2n,
    const int* __restrict__ f1, const int* __restrict__ f2, float* __restrict__ out)
{
    int s = blockIdx.x;
    float a = g1n[s], b = g2n[s];
    int s1 = f1[s], s2 = f2[s];
    int row = (s % TT)*BB + (s / TT);
    int c = threadIdx.x;
    float4 o1 = ((const float4*)(eout + (size_t)s1*DD))[c];
    float4 o2 = ((const float4*)(eout + (size_t)s2*DD))[c];
    float4 xr = ((const float4*)(x2 + (size_t)row*DD))[c];
    float4 r;
    r.x = xr.x + a*o1.x + b*o2.x;
    r.y = xr.y + a*o1.y + b*o2.y;
    r.z = xr.z + a*o1.z + b*o2.z;
    r.w = xr.w + a*o1.w + b*o2.w;
    ((float4*)(out + (size_t)row*DD))[c] = r;
}

extern "C" void kernel_launch(void* const* d_in, const int* in_sizes, int n_in,
                              void* d_out, int out_size, void* d_ws, size_t ws_size,
                              hipStream_t stream)
{
    const float* x    = (const float*)d_in[0];
    const float* Wq   = (const float*)d_in[1];
    const float* bq   = (const float*)d_in[2];
    const float* Wk   = (const float*)d_in[3];
    const float* bk   = (const float*)d_in[4];
    const float* Wv   = (const float*)d_in[5];
    const float* bv   = (const float*)d_in[6];
    const float* Wo   = (const float*)d_in[7];
    const float* bo   = (const float*)d_in[8];
    const float* ln1g = (const float*)d_in[9];
    const float* ln1b = (const float*)d_in[10];
    const float* ln2g = (const float*)d_in[11];
    const float* ln2b = (const float*)d_in[12];
    const float* wgm  = (const float*)d_in[13];
    const float* W1   = (const float*)d_in[14];
    const float* b1   = (const float*)d_in[15];
    const float* W2   = (const float*)d_in[16];
    const float* b2   = (const float*)d_in[17];
    float* out = (float*)d_out;

    char* w = (char*)d_ws;
    float*          h1   = (float*)(w);                        // 16MB (attn out too)
    float*          qb   = (float*)(w + ((size_t)16<<20));     // 16MB (q, then h2)
    float*          kb   = (float*)(w + ((size_t)32<<20));     // 16MB (k, then ffno lo)
    float*          vb   = (float*)(w + ((size_t)48<<20));     // 16MB (v, then ffno hi)
    float*          x2   = (float*)(w + ((size_t)64<<20));     // 16MB
    unsigned short* bufb = (unsigned short*)(w + ((size_t)80<<20));   // 16MB bf16 [8192,1024]
    unsigned short* hb   = (unsigned short*)(w + ((size_t)96<<20));   // 64MB bf16 [8192,4096]
    unsigned short* W1t  = (unsigned short*)(w + ((size_t)160<<20));  // 64MB bf16 [8][4096][1024]
    unsigned short* W2t  = (unsigned short*)(w + ((size_t)224<<20));  // 64MB bf16 [8][1024][4096]
    float*          ffno = kb;                                 // 32MB f32 [8192,1024] (reuses k+v)
    char*  sm   = w + ((size_t)288<<20);
    float* gates   = (float*)(sm);                sm += (size_t)SS*EE*4;
    int*   idx1    = (int*)(sm);                  sm += SS*4;
    int*   idx2    = (int*)(sm);                  sm += SS*4;
    float* g1      = (float*)(sm);                sm += SS*4;
    float* g2      = (float*)(sm);                sm += SS*4;
    float* g1n     = (float*)(sm);                sm += SS*4;
    float* g2n     = (float*)(sm);                sm += SS*4;
    int*   f1      = (int*)(sm);                  sm += SS*4;
    int*   f2      = (int*)(sm);                  sm += SS*4;
    int*   slot2row= (int*)(sm);                  sm += EE*CAP*4;

    dim3 gProj(DD/64, SS/64);
    // 0. weight transposes+bf16 (independent; issue first)
    transpose_bf16_k<<<dim3(FF/64, DD/64, EE), 256, 0, stream>>>(W1, W1t, DD, FF);
    transpose_bf16_k<<<dim3(DD/64, FF/64, EE), 256, 0, stream>>>(W2, W2t, FF, DD);
    // 1. LN1
    ln_kernel<<<SS, 256, 0, stream>>>(x, ln1g, ln1b, h1);
    // 2-4. Q,K,V projections (f32, routing-critical path unchanged)
    gemm_f32<false,false><<<gProj, 256, 0, stream>>>(h1, Wq, bq, nullptr, nullptr, qb,
        SS, DD, DD, 0.125f, 0, 0, 1<<30);
    gemm_f32<false,false><<<gProj, 256, 0, stream>>>(h1, Wk, bk, nullptr, nullptr, kb,
        SS, DD, DD, 1.0f, 0, 0, 1<<30);
    gemm_f32<false,false><<<gProj, 256, 0, stream>>>(h1, Wv, bv, nullptr, nullptr, vb,
        SS, DD, DD, 1.0f, 0, 0, 1<<30);
    // 5. attention -> h1
    attn_kernel<<<dim3(TT/64, BB*HH), 256, 0, stream>>>(qb, kb, vb, h1);
    // 6. O-projection + residual -> x2
    gemm_f32<false,false><<<gProj, 256, 0, stream>>>(h1, Wo, bo, x, nullptr, x2,
        SS, DD, DD, 1.0f, 0, 0, 1<<30);
    // 7. LN2 -> h2 (qb)
    ln_kernel<<<SS, 256, 0, stream>>>(x2, ln2g, ln2b, qb);
    // 8. routing
    route_kernel<<<SS/4, 256, 0, stream>>>(qb, wgm, gates, idx1, idx2, g1, g2);
    // 9. scan -> positions/capacity/slot map/l_aux
    scan_kernel<<<1, 256, 0, stream>>>(gates, idx1, idx2, g1, g2,
        g1n, g2n, f1, f2, slot2row, out + (size_t)SS*DD);
    // 9b. gather dispatch buffer (bf16, zero for empty slots)
    gather_bf16_k<<<EE*CAP, 256, 0, stream>>>(qb, slot2row, bufb);
    // 10. expert GEMM1 (bf16 MFMA, relu, bf16 out): [8192,4096] = buf @ W1
    gemm_mfma<true,true><<<dim3(FF/128, (EE*CAP)/128), 256, 0, stream>>>(
        bufb, W1t, b1, nullptr, hb, EE*CAP, FF, DD, (long)FF*DD, FF, CAP);
    // 11. expert GEMM2 (bf16 MFMA, f32 out): [8192,1024] = h @ W2
    gemm_mfma<false,false><<<dim3(DD/128, (EE*CAP)/128), 256, 0, stream>>>(
        hb, W2t, b2, ffno, nullptr, EE*CAP, DD, FF, (long)DD*FF, DD, CAP);
    // 12. combine + residual -> out
    combine_kernel<<<SS, 256, 0, stream>>>(x2, ffno, g1n, g2n, f1, f2, out);
    (void)in_sizes; (void)n_in; (void)out_size; (void)ws_size;
}

// Round 3
// 686.729 us; speedup vs baseline: 5.0633x; 2.3238x over previous
//
#include <hip/hip_runtime.h>

#define TT 2048
#define BB 2
#define DD 1024
#define HH 16
#define HD 64
#define FF 4096
#define EE 8
#define SS (TT*BB)     // 4096 tokens
#define CAP 1024       // 2*ceil(S/E)
#define EPSF 1.1920929e-07f

typedef __attribute__((ext_vector_type(8))) short short8;
typedef __attribute__((ext_vector_type(4))) float floatx4;

static __device__ inline unsigned short f2bf(float f){
    unsigned int u = __float_as_uint(f);
    unsigned int r = (u + 0x7fffu + ((u>>16)&1u)) >> 16;
    return (unsigned short)r;
}
static __device__ inline float bf2f(unsigned short h){
    return __uint_as_float(((unsigned int)h)<<16);
}
static __device__ inline void split2(float x, unsigned short& h, unsigned short& l){
    unsigned short hh = f2bf(x);
    h = hh;
    l = f2bf(x - bf2f(hh));
}
#define GETF4(v,j) ((j)==0?(v).x:(j)==1?(v).y:(j)==2?(v).z:(v).w)

// ---------------- LayerNorm ---------------------------------------------------
__global__ __launch_bounds__(256) void ln_kernel(const float* __restrict__ x,
    const float* __restrict__ gam, const float* __restrict__ bet, float* __restrict__ o)
{
    int row = blockIdx.x;
    int tid = threadIdx.x;
    float4 v = ((const float4*)(x + (size_t)row*DD))[tid];
    float s  = v.x+v.y+v.z+v.w;
    float ss = v.x*v.x+v.y*v.y+v.z*v.z+v.w*v.w;
    __shared__ float r1[256], r2[256];
    r1[tid]=s; r2[tid]=ss;
    __syncthreads();
    for (int off=128; off>0; off>>=1){
        if (tid<off){ r1[tid]+=r1[tid+off]; r2[tid]+=r2[tid+off]; }
        __syncthreads();
    }
    float mean = r1[0] * (1.f/DD);
    float var  = r2[0] * (1.f/DD) - mean*mean;
    float inv  = 1.f / sqrtf(var + 1e-5f);
    float4 g = ((const float4*)gam)[tid];
    float4 b = ((const float4*)bet)[tid];
    float4 r;
    r.x = (v.x-mean)*inv*g.x + b.x;
    r.y = (v.y-mean)*inv*g.y + b.y;
    r.z = (v.z-mean)*inv*g.z + b.z;
    r.w = (v.w-mean)*inv*g.w + b.w;
    ((float4*)(o + (size_t)row*DD))[tid] = r;
}

// ---------------- plain bf16 MFMA GEMM (FFN; proven R2) ----------------------
template<bool RELU, bool OUTBF16>
__global__ __launch_bounds__(256) void gemm_mfma(
    const unsigned short* __restrict__ A, const unsigned short* __restrict__ Bt,
    const float* __restrict__ bias, float* __restrict__ Cf,
    unsigned short* __restrict__ Cb,
    int M, int N, int K, long wStride, int bStride, int rowsPerExp)
{
    __shared__ unsigned short As[128*64];
    __shared__ unsigned short Bs[128*64];
    const int tid = threadIdx.x, lane = tid&63;
    const int w = tid>>6, wr = w>>1, wc = w&1;
    const int m0 = blockIdx.y*128, n0 = blockIdx.x*128;
    const int e = m0 / rowsPerExp;
    const unsigned short* Bp = Bt + (size_t)e*wStride;
    const int srow = tid>>3, sslot = tid&7;
    floatx4 zf = {0.f,0.f,0.f,0.f};
    floatx4 acc[4][4];
    #pragma unroll
    for (int m=0;m<4;m++)
        #pragma unroll
        for (int n=0;n<4;n++) acc[m][n]=zf;

    short8 ar[4], br[4];
    #pragma unroll
    for (int i=0;i<4;i++){
        int r = srow + i*32;
        ar[i] = *(const short8*)(A  + (size_t)(m0+r)*K + sslot*8);
        br[i] = *(const short8*)(Bp + (size_t)(n0+r)*K + sslot*8);
    }
    const int NT = K/64;
    for (int kt=0; kt<NT; kt++){
        __syncthreads();
        #pragma unroll
        for (int i=0;i<4;i++){
            int r = srow + i*32;
            int off = r*64 + ((sslot ^ (r&7))<<3);
            *(short8*)(&As[off]) = ar[i];
            *(short8*)(&Bs[off]) = br[i];
        }
        __syncthreads();
        if (kt+1 < NT){
            int k0 = (kt+1)*64;
            #pragma unroll
            for (int i=0;i<4;i++){
                int r = srow + i*32;
                ar[i] = *(const short8*)(A  + (size_t)(m0+r)*K + k0 + sslot*8);
                br[i] = *(const short8*)(Bp + (size_t)(n0+r)*K + k0 + sslot*8);
            }
        }
        #pragma unroll
        for (int kk=0;kk<2;kk++){
            short8 af[4], bf[4];
            int kgrp = kk*4 + (lane>>4);
            #pragma unroll
            for (int m=0;m<4;m++){
                int rowa = wr*64 + m*16 + (lane&15);
                af[m] = *(const short8*)(&As[rowa*64 + ((kgrp ^ (rowa&7))<<3)]);
                int rowb = wc*64 + m*16 + (lane&15);
                bf[m] = *(const short8*)(&Bs[rowb*64 + ((kgrp ^ (rowb&7))<<3)]);
            }
            #pragma unroll
            for (int m=0;m<4;m++)
                #pragma unroll
                for (int n=0;n<4;n++)
                    acc[m][n] = __builtin_amdgcn_mfma_f32_16x16x32_bf16(af[m], bf[n], acc[m][n], 0,0,0);
        }
    }
    int colg = n0 + wc*64 + (lane&15);
    int rowg = m0 + wr*64 + ((lane>>4)<<2);
    #pragma unroll
    for (int n=0;n<4;n++){
        float bv = bias[e*bStride + colg + n*16];
        #pragma unroll
        for (int m=0;m<4;m++){
            #pragma unroll
            for (int i2=0;i2<4;i2++){
                float v = acc[m][n][i2] + bv;
                if (RELU) v = fmaxf(v, 0.f);
                size_t o = (size_t)(rowg + m*16 + i2)*N + colg + n*16;
                if (OUTBF16) Cb[o] = f2bf(v); else Cf[o] = v;
            }
        }
    }
}

// ---------------- split-bf16x4 MFMA GEMM (fp32-fidelity) ---------------------
// A f32 [M,K] (split in-kernel). Bhi/Blo bf16 [Ntot][K].
// QKV=true: Ntot=3072, chunk c=n0>>10 selects (out,bias,scale={.125,1,1}).
// QKV=false: single out o0 with bias b0 + residual res.
template<bool QKV>
__global__ __launch_bounds__(256) void gemm_mfma_s(
    const float* __restrict__ A,
    const unsigned short* __restrict__ Bhi, const unsigned short* __restrict__ Blo,
    const float* __restrict__ b0, const float* __restrict__ b1p, const float* __restrict__ b2p,
    const float* __restrict__ res,
    float* __restrict__ o0, float* __restrict__ o1, float* __restrict__ o2,
    int M, int K)
{
    __shared__ unsigned short As[128*64];   // row: [hi k0..31 | lo k0..31] octet-swizzled
    __shared__ unsigned short Bs[128*64];
    const int tid = threadIdx.x, lane = tid&63;
    const int w = tid>>6, wr = w>>1, wc = w&1;
    const int m0 = blockIdx.y*128, n0 = blockIdx.x*128;
    const int row = tid>>1, khalf = tid&1;
    floatx4 zf = {0.f,0.f,0.f,0.f};
    floatx4 acc[4][4];
    #pragma unroll
    for (int m=0;m<4;m++)
        #pragma unroll
        for (int n=0;n<4;n++) acc[m][n]=zf;

    float4 aw0,aw1,aw2,aw3;
    short8 bwh0,bwh1,bwl0,bwl1;
    {
        const float* ap = A + (size_t)(m0+row)*K + khalf*16;
        aw0 = ((const float4*)ap)[0]; aw1 = ((const float4*)ap)[1];
        aw2 = ((const float4*)ap)[2]; aw3 = ((const float4*)ap)[3];
        const unsigned short* bh = Bhi + (size_t)(n0+row)*K + khalf*16;
        const unsigned short* bl = Blo + (size_t)(n0+row)*K + khalf*16;
        bwh0 = *(const short8*)(bh); bwh1 = *(const short8*)(bh+8);
        bwl0 = *(const short8*)(bl); bwl1 = *(const short8*)(bl+8);
    }
    const int NT = K/32;
    for (int kt=0; kt<NT; kt++){
        __syncthreads();
        {
            unsigned short h[16], l[16];
            #pragma unroll
            for (int j=0;j<4;j++){ split2(GETF4(aw0,j), h[j],   l[j]); }
            #pragma unroll
            for (int j=0;j<4;j++){ split2(GETF4(aw1,j), h[4+j], l[4+j]); }
            #pragma unroll
            for (int j=0;j<4;j++){ split2(GETF4(aw2,j), h[8+j], l[8+j]); }
            #pragma unroll
            for (int j=0;j<4;j++){ split2(GETF4(aw3,j), h[12+j],l[12+j]); }
            int base = row*64, sw = row&7;
            int g0 = khalf*2, g1 = khalf*2+1;
            *(short8*)(&As[base + ((g0^sw)<<3)])     = *(short8*)(&h[0]);
            *(short8*)(&As[base + ((g1^sw)<<3)])     = *(short8*)(&h[8]);
            *(short8*)(&As[base + (((g0+4)^sw)<<3)]) = *(short8*)(&l[0]);
            *(short8*)(&As[base + (((g1+4)^sw)<<3)]) = *(short8*)(&l[8]);
            *(short8*)(&Bs[base + ((g0^sw)<<3)])     = bwh0;
            *(short8*)(&Bs[base + ((g1^sw)<<3)])     = bwh1;
            *(short8*)(&Bs[base + (((g0+4)^sw)<<3)]) = bwl0;
            *(short8*)(&Bs[base + (((g1+4)^sw)<<3)]) = bwl1;
        }
        __syncthreads();
        if (kt+1 < NT){
            int k0 = (kt+1)*32;
            const float* ap = A + (size_t)(m0+row)*K + k0 + khalf*16;
            aw0 = ((const float4*)ap)[0]; aw1 = ((const float4*)ap)[1];
            aw2 = ((const float4*)ap)[2]; aw3 = ((const float4*)ap)[3];
            const unsigned short* bh = Bhi + (size_t)(n0+row)*K + k0 + khalf*16;
            const unsigned short* bl = Blo + (size_t)(n0+row)*K + k0 + khalf*16;
            bwh0 = *(const short8*)(bh); bwh1 = *(const short8*)(bh+8);
            bwl0 = *(const short8*)(bl); bwl1 = *(const short8*)(bl+8);
        }
        {
            int kg = lane>>4;
            short8 afh[4], afl[4], bfh[4], bfl[4];
            #pragma unroll
            for (int m=0;m<4;m++){
                int ra = wr*64 + m*16 + (lane&15);
                afh[m] = *(const short8*)(&As[ra*64 + ((kg ^ (ra&7))<<3)]);
                afl[m] = *(const short8*)(&As[ra*64 + (((kg+4) ^ (ra&7))<<3)]);
                int rb = wc*64 + m*16 + (lane&15);
                bfh[m] = *(const short8*)(&Bs[rb*64 + ((kg ^ (rb&7))<<3)]);
                bfl[m] = *(const short8*)(&Bs[rb*64 + (((kg+4) ^ (rb&7))<<3)]);
            }
            #pragma unroll
            for (int m=0;m<4;m++)
                #pragma unroll
                for (int n=0;n<4;n++){
                    acc[m][n] = __builtin_amdgcn_mfma_f32_16x16x32_bf16(afl[m], bfl[n], acc[m][n], 0,0,0);
                    acc[m][n] = __builtin_amdgcn_mfma_f32_16x16x32_bf16(afl[m], bfh[n], acc[m][n], 0,0,0);
                    acc[m][n] = __builtin_amdgcn_mfma_f32_16x16x32_bf16(afh[m], bfl[n], acc[m][n], 0,0,0);
                    acc[m][n] = __builtin_amdgcn_mfma_f32_16x16x32_bf16(afh[m], bfh[n], acc[m][n], 0,0,0);
                }
        }
    }
    int colg = n0 + wc*64 + (lane&15);
    int rowg = m0 + wr*64 + ((lane>>4)<<2);
    const float* bp; float* op; float scale; int colc;
    if (QKV){
        int chunk = n0>>10;
        bp = chunk==0 ? b0 : (chunk==1 ? b1p : b2p);
        op = chunk==0 ? o0 : (chunk==1 ? o1 : o2);
        scale = chunk==0 ? 0.125f : 1.0f;
        colc = colg & 1023;
    } else { bp = b0; op = o0; scale = 1.0f; colc = colg; }
    #pragma unroll
    for (int n=0;n<4;n++){
        float bv = bp[colc + n*16];
        #pragma unroll
        for (int m=0;m<4;m++){
            #pragma unroll
            for (int i2=0;i2<4;i2++){
                float v = (acc[m][n][i2] + bv)*scale;
                int r = rowg + m*16 + i2;
                if (!QKV) v += res[(size_t)r*DD + colc + n*16];
                op[(size_t)r*DD + colc + n*16] = v;
            }
        }
    }
}

// ---------------- split-bf16x4 MFMA flash attention --------------------------
// Grid (T/64, B*H), 256 thr = 4 waves x 16 q-rows. Q frags in regs (hi/lo).
// K LDS [key][d] hi/lo; V LDS transposed [d][key] hi/lo; P via per-wave LDS.
__global__ __launch_bounds__(256) void attn_mfma(const float* __restrict__ q,
    const float* __restrict__ k, const float* __restrict__ v, float* __restrict__ o)
{
    __shared__ unsigned short Kh[64*64], Kl[64*64];
    __shared__ unsigned short Vh[64*64], Vl[64*64];
    __shared__ unsigned short Ph[4*16*64], Pl[4*16*64];
    const int tid = threadIdx.x, lane = tid&63, w = tid>>6;
    const int t0 = blockIdx.x*64;
    const int b = blockIdx.y>>4, h = blockIdx.y&15;

    // Q fragments in registers: row=lane&15 (wave strip), k=kk*32+(lane>>4)*8+j
    short8 qh[2], ql[2];
    #pragma unroll
    for (int kk=0;kk<2;kk++){
        const float* qp = q + ((size_t)(t0 + 16*w + (lane&15))*BB + b)*DD + h*64 + kk*32 + (lane>>4)*8;
        float4 f0 = ((const float4*)qp)[0];
        float4 f1 = ((const float4*)qp)[1];
        unsigned short hh[8], ll[8];
        #pragma unroll
        for (int j=0;j<4;j++){ split2(GETF4(f0,j), hh[j], ll[j]); }
        #pragma unroll
        for (int j=0;j<4;j++){ split2(GETF4(f1,j), hh[4+j], ll[4+j]); }
        qh[kk] = *(short8*)hh; ql[kk] = *(short8*)ll;
    }

    // staging indices
    const int kr = tid>>2, kq = tid&3;          // K: row kr, d-quarter kq
    const int vs0 = (tid&15)*4, vd0 = (tid>>4)*4; // V: 4s x 4d block
    float4 kw0,kw1,kw2,kw3, vw0,vw1,vw2,vw3;
    {
        const float* kp = k + ((size_t)(0 + kr)*BB + b)*DD + h*64 + kq*16;
        kw0=((const float4*)kp)[0]; kw1=((const float4*)kp)[1];
        kw2=((const float4*)kp)[2]; kw3=((const float4*)kp)[3];
        const float* vp = v + ((size_t)(0 + vs0)*BB + b)*DD + h*64 + vd0;
        vw0=*(const float4*)(vp);
        vw1=*(const float4*)(vp + (size_t)BB*DD);
        vw2=*(const float4*)(vp + (size_t)2*BB*DD);
        vw3=*(const float4*)(vp + (size_t)3*BB*DD);
    }

    float m_st[4] = {-3.0e38f,-3.0e38f,-3.0e38f,-3.0e38f};
    float l_st[4] = {0.f,0.f,0.f,0.f};
    floatx4 zf = {0.f,0.f,0.f,0.f};
    floatx4 oacc[4]; 
    #pragma unroll
    for (int n=0;n<4;n++) oacc[n]=zf;

    for (int s0=0; s0<TT; s0+=64){
        __syncthreads();
        // ---- stage K (split) ----
        {
            unsigned short hh[16], ll[16];
            #pragma unroll
            for (int j=0;j<4;j++){ split2(GETF4(kw0,j), hh[j],   ll[j]); }
            #pragma unroll
            for (int j=0;j<4;j++){ split2(GETF4(kw1,j), hh[4+j], ll[4+j]); }
            #pragma unroll
            for (int j=0;j<4;j++){ split2(GETF4(kw2,j), hh[8+j], ll[8+j]); }
            #pragma unroll
            for (int j=0;j<4;j++){ split2(GETF4(kw3,j), hh[12+j],ll[12+j]); }
            int base = kr*64, sw = kr&7;
            int g0 = kq*2, g1 = kq*2+1;
            *(short8*)(&Kh[base + ((g0^sw)<<3)]) = *(short8*)(&hh[0]);
            *(short8*)(&Kh[base + ((g1^sw)<<3)]) = *(short8*)(&hh[8]);
            *(short8*)(&Kl[base + ((g0^sw)<<3)]) = *(short8*)(&ll[0]);
            *(short8*)(&Kl[base + ((g1^sw)<<3)]) = *(short8*)(&ll[8]);
        }
        // ---- stage V transposed (split) ----
        {
            int g = vs0>>3, so = vs0&7;
            #pragma unroll
            for (int j=0;j<4;j++){
                int d = vd0 + j;
                unsigned short h0,h1,h2,h3, l0,l1,l2,l3;
                split2(GETF4(vw0,j), h0,l0);
                split2(GETF4(vw1,j), h1,l1);
                split2(GETF4(vw2,j), h2,l2);
                split2(GETF4(vw3,j), h3,l3);
                ushort4 hv; hv.x=h0; hv.y=h1; hv.z=h2; hv.w=h3;
                ushort4 lv; lv.x=l0; lv.y=l1; lv.z=l2; lv.w=l3;
                int off = d*64 + ((g ^ (d&7))<<3) + so;
                *(ushort4*)(&Vh[off]) = hv;
                *(ushort4*)(&Vl[off]) = lv;
            }
        }
        __syncthreads();
        // ---- prefetch next K/V tile ----
        if (s0+64 < TT){
            const float* kp = k + ((size_t)(s0+64 + kr)*BB + b)*DD + h*64 + kq*16;
            kw0=((const float4*)kp)[0]; kw1=((const float4*)kp)[1];
            kw2=((const float4*)kp)[2]; kw3=((const float4*)kp)[3];
            const float* vp = v + ((size_t)(s0+64 + vs0)*BB + b)*DD + h*64 + vd0;
            vw0=*(const float4*)(vp);
            vw1=*(const float4*)(vp + (size_t)BB*DD);
            vw2=*(const float4*)(vp + (size_t)2*BB*DD);
            vw3=*(const float4*)(vp + (size_t)3*BB*DD);
        }
        // ---- QK^T: S strip 16x64, 4-term split ----
        floatx4 sacc[4];
        #pragma unroll
        for (int n=0;n<4;n++){
            floatx4 s = zf;
            #pragma unroll
            for (int kk=0;kk<2;kk++){
                int g = kk*4 + (lane>>4);
                int rb = n*16 + (lane&15);
                short8 kbh = *(const short8*)(&Kh[rb*64 + ((g ^ (rb&7))<<3)]);
                short8 kbl = *(const short8*)(&Kl[rb*64 + ((g ^ (rb&7))<<3)]);
                s = __builtin_amdgcn_mfma_f32_16x16x32_bf16(ql[kk], kbl, s, 0,0,0);
                s = __builtin_amdgcn_mfma_f32_16x16x32_bf16(ql[kk], kbh, s, 0,0,0);
                s = __builtin_amdgcn_mfma_f32_16x16x32_bf16(qh[kk], kbl, s, 0,0,0);
                s = __builtin_amdgcn_mfma_f32_16x16x32_bf16(qh[kk], kbh, s, 0,0,0);
            }
            sacc[n] = s;
        }
        // ---- online softmax (rows = (lane>>4)*4+r, cols across 16-lane group) ----
        float mx[4];
        #pragma unroll
        for (int r=0;r<4;r++)
            mx[r] = fmaxf(fmaxf(sacc[0][r], sacc[1][r]), fmaxf(sacc[2][r], sacc[3][r]));
        #pragma unroll
        for (int sh=1; sh<16; sh<<=1){
            #pragma unroll
            for (int r=0;r<4;r++) mx[r] = fmaxf(mx[r], __shfl_xor(mx[r], sh));
        }
        float corr[4];
        #pragma unroll
        for (int r=0;r<4;r++){
            float nm = fmaxf(m_st[r], mx[r]);
            corr[r] = __expf(m_st[r] - nm);
            m_st[r] = nm;
        }
        float ts[4] = {0.f,0.f,0.f,0.f};
        #pragma unroll
        for (int n=0;n<4;n++){
            #pragma unroll
            for (int r=0;r<4;r++){
                float p = __expf(sacc[n][r] - m_st[r]);
                ts[r] += p;
                unsigned short ph, pl;
                split2(p, ph, pl);
                int q2 = ((lane>>4)<<2) + r;
                int s2 = n*16 + (lane&15);
                int off = w*1024 + q2*64 + (((s2>>3) ^ (q2&7))<<3) + (s2&7);
                Ph[off] = ph; Pl[off] = pl;
            }
        }
        #pragma unroll
        for (int sh=1; sh<16; sh<<=1){
            #pragma unroll
            for (int r=0;r<4;r++) ts[r] += __shfl_xor(ts[r], sh);
        }
        #pragma unroll
        for (int r=0;r<4;r++) l_st[r] = l_st[r]*corr[r] + ts[r];
        #pragma unroll
        for (int n=0;n<4;n++)
            #pragma unroll
            for (int r=0;r<4;r++) oacc[n][r] *= corr[r];
        // ---- PV: O strip 16x64, 4-term split ----
        #pragma unroll
        for (int kk=0;kk<2;kk++){
            int g = kk*4 + (lane>>4);
            int rq = lane&15;
            short8 pah = *(const short8*)(&Ph[w*1024 + rq*64 + ((g ^ (rq&7))<<3)]);
            short8 pal = *(const short8*)(&Pl[w*1024 + rq*64 + ((g ^ (rq&7))<<3)]);
            #pragma unroll
            for (int n=0;n<4;n++){
                int rd = n*16 + (lane&15);
                short8 vbh = *(const short8*)(&Vh[rd*64 + ((g ^ (rd&7))<<3)]);
                short8 vbl = *(const short8*)(&Vl[rd*64 + ((g ^ (rd&7))<<3)]);
                oacc[n] = __builtin_amdgcn_mfma_f32_16x16x32_bf16(pal, vbl, oacc[n], 0,0,0);
                oacc[n] = __builtin_amdgcn_mfma_f32_16x16x32_bf16(pal, vbh, oacc[n], 0,0,0);
                oacc[n] = __builtin_amdgcn_mfma_f32_16x16x32_bf16(pah, vbl, oacc[n], 0,0,0);
                oacc[n] = __builtin_amdgcn_mfma_f32_16x16x32_bf16(pah, vbh, oacc[n], 0,0,0);
            }
        }
    }
    // ---- epilogue ----
    float il[4];
    #pragma unroll
    for (int r=0;r<4;r++) il[r] = 1.f/l_st[r];
    int qrow = t0 + 16*w + ((lane>>4)<<2);
    #pragma unroll
    for (int n=0;n<4;n++){
        #pragma unroll
        for (int r=0;r<4;r++){
            o[((size_t)(qrow+r)*BB + b)*DD + h*64 + n*16 + (lane&15)] = oacc[n][r]*il[r];
        }
    }
}

// ---------------- transpose+convert bf16 (FFN weights; proven R2) ------------
__global__ __launch_bounds__(256) void transpose_bf16_k(const float* __restrict__ in,
    unsigned short* __restrict__ outp, int R, int C)
{
    __shared__ float t[64][65];
    int e = blockIdx.z;
    const float* ip = in + (size_t)e*R*C;
    unsigned short* op = outp + (size_t)e*R*C;
    int r0 = blockIdx.y*64, c0 = blockIdx.x*64;
    int tid = threadIdx.x;
    #pragma unroll
    for (int i=0;i<4;i++){
        int ch = i*256 + tid;
        int r = ch>>4, c4 = (ch&15)*4;
        float4 v = *(const float4*)(ip + (size_t)(r0+r)*C + c0 + c4);
        t[r][c4+0]=v.x; t[r][c4+1]=v.y; t[r][c4+2]=v.z; t[r][c4+3]=v.w;
    }
    __syncthreads();
    #pragma unroll
    for (int i=0;i<4;i++){
        int ch = i*256 + tid;
        int rr = ch>>4, c4 = (ch&15)*4;
        ushort4 o;
        o.x = f2bf(t[c4+0][rr]); o.y = f2bf(t[c4+1][rr]);
        o.z = f2bf(t[c4+2][rr]); o.w = f2bf(t[c4+3][rr]);
        *(ushort4*)(op + (size_t)(c0+rr)*R + r0 + c4) = o;
    }
}

// ---------------- transpose + split hi/lo (projection weights) ---------------
__global__ __launch_bounds__(256) void transpose_split_k(const float* __restrict__ in,
    unsigned short* __restrict__ oh, unsigned short* __restrict__ ol, int R, int C)
{
    __shared__ float t[64][65];
    int r0 = blockIdx.y*64, c0 = blockIdx.x*64;
    int tid = threadIdx.x;
    #pragma unroll
    for (int i=0;i<4;i++){
        int ch = i*256 + tid;
        int r = ch>>4, c4 = (ch&15)*4;
        float4 v = *(const float4*)(in + (size_t)(r0+r)*C + c0 + c4);
        t[r][c4+0]=v.x; t[r][c4+1]=v.y; t[r][c4+2]=v.z; t[r][c4+3]=v.w;
    }
    __syncthreads();
    #pragma unroll
    for (int i=0;i<4;i++){
        int ch = i*256 + tid;
        int rr = ch>>4, c4 = (ch&15)*4;
        ushort4 hv, lv;
        split2(t[c4+0][rr], hv.x, lv.x);
        split2(t[c4+1][rr], hv.y, lv.y);
        split2(t[c4+2][rr], hv.z, lv.z);
        split2(t[c4+3][rr], hv.w, lv.w);
        size_t off = (size_t)(c0+rr)*R + r0 + c4;
        *(ushort4*)(oh + off) = hv;
        *(ushort4*)(ol + off) = lv;
    }
}

// ---------------- gather dispatch buffer -------------------------------------
__global__ __launch_bounds__(256) void gather_bf16_k(const float* __restrict__ h2,
    const int* __restrict__ s2r, unsigned short* __restrict__ buf)
{
    int s = blockIdx.x; int row = s2r[s]; int c = threadIdx.x;
    float4 v = make_float4(0.f,0.f,0.f,0.f);
    if (row>=0) v = *(const float4*)(h2 + (size_t)row*DD + c*4);
    ushort4 o;
    o.x=f2bf(v.x); o.y=f2bf(v.y); o.z=f2bf(v.z); o.w=f2bf(v.w);
    *(ushort4*)(buf + (size_t)s*DD + c*4) = o;
}

// ---------------- Routing (unchanged) ----------------------------------------
__global__ __launch_bounds__(256) void route_kernel(const float* __restrict__ h2,
    const float* __restrict__ wgm, float* __restrict__ gates,
    int* __restrict__ idx1, int* __restrict__ idx2,
    float* __restrict__ g1, float* __restrict__ g2)
{
    int wid = threadIdx.x >> 6, lane = threadIdx.x & 63;
    int s = blockIdx.x*4 + wid;
    int row = (s % TT)*BB + (s / TT);
    const float* hr = h2 + (size_t)row*DD;
    float acc[EE] = {};
    #pragma unroll
    for (int c=0;c<16;c++){
        int d = c*64 + lane;
        float xv = hr[d];
        const float* wr = wgm + (size_t)d*EE;
        #pragma unroll
        for (int e2=0;e2<EE;e2++) acc[e2] += xv * wr[e2];
    }
    #pragma unroll
    for (int off=32; off>0; off>>=1){
        #pragma unroll
        for (int e2=0;e2<EE;e2++) acc[e2] += __shfl_down(acc[e2], off);
    }
    if (lane==0){
        float mx = acc[0];
        #pragma unroll
        for (int e2=1;e2<EE;e2++) mx = fmaxf(mx, acc[e2]);
        float ex[EE]; float sum=0.f;
        #pragma unroll
        for (int e2=0;e2<EE;e2++){ ex[e2] = __expf(acc[e2]-mx); sum += ex[e2]; }
        float inv = 1.f/sum;
        int i1=0; float bv1=acc[0];
        #pragma unroll
        for (int e2=1;e2<EE;e2++){ if (acc[e2] > bv1){ bv1=acc[e2]; i1=e2; } }
        int i2=-1; float bv2=-3.0e38f;
        #pragma unroll
        for (int e2=0;e2<EE;e2++){ if (e2!=i1 && acc[e2] > bv2){ bv2=acc[e2]; i2=e2; } }
        #pragma unroll
        for (int e2=0;e2<EE;e2++) gates[(size_t)s*EE + e2] = ex[e2]*inv;
        idx1[s]=i1; idx2[s]=i2;
        g1[s]=ex[i1]*inv; g2[s]=ex[i2]*inv;
    }
}

// ---------------- Single-block deterministic scan (unchanged) ----------------
__global__ __launch_bounds__(256) void scan_kernel(
    const float* __restrict__ gates, const int* __restrict__ idx1, const int* __restrict__ idx2,
    const float* __restrict__ g1, const float* __restrict__ g2,
    float* __restrict__ g1n, float* __restrict__ g2n,
    int* __restrict__ f1, int* __restrict__ f2, int* __restrict__ slot2row,
    float* __restrict__ laux)
{
    __shared__ int i1s[SS];
    __shared__ int i2s[SS];
    __shared__ int cnt1[256][EE];
    __shared__ int cnt2[256][EE];
    __shared__ float gsum[256][EE];
    __shared__ int tot1[EE];
    int tid = threadIdx.x;
    for (int i=tid;i<EE*CAP;i+=256) slot2row[i] = -1;
    for (int i=tid;i<SS;i+=256){ i1s[i]=idx1[i]; i2s[i]=idx2[i]; }
    __syncthreads();
    int c1l[EE]={}, c2l[EE]={};
    float gl[EE]={};
    int base = tid*16;
    for (int qq=0;qq<16;qq++){
        int s = base+qq;
        c1l[i1s[s]]++; c2l[i2s[s]]++;
        #pragma unroll
        for (int e2=0;e2<EE;e2++) gl[e2] += gates[(size_t)s*EE+e2];
    }
    #pragma unroll
    for (int e2=0;e2<EE;e2++){ cnt1[tid][e2]=c1l[e2]; cnt2[tid][e2]=c2l[e2]; gsum[tid][e2]=gl[e2]; }
    __syncthreads();
    if (tid < EE){
        int e2 = tid;
        int run=0;
        for (int t=0;t<256;t++){ int tmp=cnt1[t][e2]; cnt1[t][e2]=run; run+=tmp; }
        tot1[e2]=run;
        run=0;
        for (int t=0;t<256;t++){ int tmp=cnt2[t][e2]; cnt2[t][e2]=run; run+=tmp; }
        float gr=0.f;
        for (int t=0;t<256;t++) gr += gsum[t][e2];
        gsum[0][e2]=gr;
    }
    __syncthreads();
    int p1[EE], p2[EE];
    #pragma unroll
    for (int e2=0;e2<EE;e2++){ p1[e2]=cnt1[tid][e2]; p2[e2]=cnt2[tid][e2]+tot1[e2]; }
    for (int qq=0;qq<16;qq++){
        int s = base+qq;
        int e1 = i1s[s], e2v = i2s[s];
        int pos1 = p1[e1]++;
        int pos2 = p2[e2v]++;
        float gv1 = g1[s], gv2 = g2[s];
        float gm1 = (pos1<CAP)? gv1 : 0.f;
        float gm2 = (pos2<CAP)? gv2 : 0.f;
        float den = fmaxf(gm1+gm2, EPSF);
        g1n[s] = gm1/den; g2n[s] = gm2/den;
        int ff1 = e1*CAP + (pos1<CAP?pos1:CAP-1);
        int ff2 = e2v*CAP + (pos2<CAP?pos2:CAP-1);
        f1[s]=ff1; f2[s]=ff2;
        int hrow = (s % TT)*BB + (s / TT);
        if (pos1<CAP) slot2row[ff1]=hrow;
        if (pos2<CAP) slot2row[ff2]=hrow;
    }
    if (tid==0){
        float a=0.f;
        #pragma unroll
        for (int e2=0;e2<EE;e2++) a += (gsum[0][e2]*(1.f/SS)) * ((float)tot1[e2]*(1.f/SS));
        laux[0] = a * (float)EE;
    }
}

// ---------------- Combine (unchanged) ----------------------------------------
__global__ __launch_bounds__(256) void combine_kernel(const float* __restrict__ x2,
    const float* __restrict__ eout, const float* __restrict__ g1n, const float* __restrict__ g2n,
    const int* __restrict__ f1, const int* __restrict__ f2, float* __restrict__ out)
{
    int s = blockIdx.x;
    float a = g1n[s], b = g2n[s];
    int s1 = f1[s], s2 = f2[s];
    int row = (s % TT)*BB + (s / TT);
    int c = threadIdx.x;
    float4 o1 = ((const float4*)(eout + (size_t)s1*DD))[c];
    float4 o2 = ((const float4*)(eout + (size_t)s2*DD))[c];
    float4 xr = ((const float4*)(x2 + (size_t)row*DD))[c];
    float4 r;
    r.x = xr.x + a*o1.x + b*o2.x;
    r.y = xr.y + a*o1.y + b*o2.y;
    r.z = xr.z + a*o1.z + b*o2.z;
    r.w = xr.w + a*o1.w + b*o2.w;
    ((float4*)(out + (size_t)row*DD))[c] = r;
}

extern "C" void kernel_launch(void* const* d_in, const int* in_sizes, int n_in,
                              void* d_out, int out_size, void* d_ws, size_t ws_size,
                              hipStream_t stream)
{
    const float* x    = (const float*)d_in[0];
    const float* Wq   = (const float*)d_in[1];
    const float* bq   = (const float*)d_in[2];
    const float* Wk   = (const float*)d_in[3];
    const float* bk   = (const float*)d_in[4];
    const float* Wv   = (const float*)d_in[5];
    const float* bv   = (const float*)d_in[6];
    const float* Wo   = (const float*)d_in[7];
    const float* bo   = (const float*)d_in[8];
    const float* ln1g = (const float*)d_in[9];
    const float* ln1b = (const float*)d_in[10];
    const float* ln2g = (const float*)d_in[11];
    const float* ln2b = (const float*)d_in[12];
    const float* wgm  = (const float*)d_in[13];
    const float* W1   = (const float*)d_in[14];
    const float* b1   = (const float*)d_in[15];
    const float* W2   = (const float*)d_in[16];
    const float* b2   = (const float*)d_in[17];
    float* out = (float*)d_out;

    char* w = (char*)d_ws;
    float*          h1   = (float*)(w);                        // 16MB (LN1 out / attn out)
    float*          qb   = (float*)(w + ((size_t)16<<20));     // 16MB (q, then h2)
    float*          kb   = (float*)(w + ((size_t)32<<20));     // 16MB (k; later ffno lo)
    float*          vb   = (float*)(w + ((size_t)48<<20));     // 16MB (v; later ffno hi)
    float*          x2   = (float*)(w + ((size_t)64<<20));     // 16MB
    unsigned short* bufb = (unsigned short*)(w + ((size_t)80<<20));   // 16MB bf16 dispatch
    unsigned short* hb   = (unsigned short*)(w + ((size_t)96<<20));   // 64MB bf16 FFN1 out
    // projection weight splits live in hb's region until FFN1 (written later):
    unsigned short* Bqkv_hi = (unsigned short*)(w + ((size_t)96<<20));   // 6MB [3072][1024]
    unsigned short* Bqkv_lo = (unsigned short*)(w + ((size_t)102<<20));  // 6MB
    unsigned short* Bo_hi   = (unsigned short*)(w + ((size_t)108<<20));  // 2MB [1024][1024]
    unsigned short* Bo_lo   = (unsigned short*)(w + ((size_t)110<<20));  // 2MB
    unsigned short* W1t  = (unsigned short*)(w + ((size_t)160<<20));  // 64MB
    unsigned short* W2t  = (unsigned short*)(w + ((size_t)224<<20));  // 64MB
    float*          ffno = kb;                                 // 32MB f32 (reuses k+v)
    char*  sm   = w + ((size_t)288<<20);
    float* gates   = (float*)(sm);                sm += (size_t)SS*EE*4;
    int*   idx1    = (int*)(sm);                  sm += SS*4;
    int*   idx2    = (int*)(sm);                  sm += SS*4;
    float* g1      = (float*)(sm);                sm += SS*4;
    float* g2      = (float*)(sm);                sm += SS*4;
    float* g1n     = (float*)(sm);                sm += SS*4;
    float* g2n     = (float*)(sm);                sm += SS*4;
    int*   f1      = (int*)(sm);                  sm += SS*4;
    int*   f2      = (int*)(sm);                  sm += SS*4;
    int*   slot2row= (int*)(sm);                  sm += EE*CAP*4;

    // 0. weight prep
    transpose_bf16_k<<<dim3(FF/64, DD/64, EE), 256, 0, stream>>>(W1, W1t, DD, FF);
    transpose_bf16_k<<<dim3(DD/64, FF/64, EE), 256, 0, stream>>>(W2, W2t, FF, DD);
    transpose_split_k<<<dim3(16,16), 256, 0, stream>>>(Wq, Bqkv_hi,                Bqkv_lo,                DD, DD);
    transpose_split_k<<<dim3(16,16), 256, 0, stream>>>(Wk, Bqkv_hi + (size_t)DD*DD,   Bqkv_lo + (size_t)DD*DD,   DD, DD);
    transpose_split_k<<<dim3(16,16), 256, 0, stream>>>(Wv, Bqkv_hi + (size_t)2*DD*DD, Bqkv_lo + (size_t)2*DD*DD, DD, DD);
    transpose_split_k<<<dim3(16,16), 256, 0, stream>>>(Wo, Bo_hi, Bo_lo, DD, DD);
    // 1. LN1
    ln_kernel<<<SS, 256, 0, stream>>>(x, ln1g, ln1b, h1);
    // 2. fused QKV projection (split-bf16x4 MFMA)
    gemm_mfma_s<true><<<dim3(24, SS/128), 256, 0, stream>>>(
        h1, Bqkv_hi, Bqkv_lo, bq, bk, bv, nullptr, qb, kb, vb, SS, DD);
    // 3. attention (split-bf16x4 MFMA flash) -> h1
    attn_mfma<<<dim3(TT/64, BB*HH), 256, 0, stream>>>(qb, kb, vb, h1);
    // 4. O-projection + residual (split-bf16x4 MFMA) -> x2
    gemm_mfma_s<false><<<dim3(8, SS/128), 256, 0, stream>>>(
        h1, Bo_hi, Bo_lo, bo, bo, bo, x, x2, x2, x2, SS, DD);
    // 5. LN2 -> h2 (qb)
    ln_kernel<<<SS, 256, 0, stream>>>(x2, ln2g, ln2b, qb);
    // 6. routing
    route_kernel<<<SS/4, 256, 0, stream>>>(qb, wgm, gates, idx1, idx2, g1, g2);
    // 7. scan
    scan_kernel<<<1, 256, 0, stream>>>(gates, idx1, idx2, g1, g2,
        g1n, g2n, f1, f2, slot2row, out + (size_t)SS*DD);
    // 8. gather dispatch buffer
    gather_bf16_k<<<EE*CAP, 256, 0, stream>>>(qb, slot2row, bufb);
    // 9. expert FFN (plain bf16 MFMA)
    gemm_mfma<true,true><<<dim3(FF/128, (EE*CAP)/128), 256, 0, stream>>>(
        bufb, W1t, b1, nullptr, hb, EE*CAP, FF, DD, (long)FF*DD, FF, CAP);
    gemm_mfma<false,false><<<dim3(DD/128, (EE*CAP)/128), 256, 0, stream>>>(
        hb, W2t, b2, ffno, nullptr, EE*CAP, DD, FF, (long)DD*FF, DD, CAP);
    // 10. combine + residual
    combine_kernel<<<SS, 256, 0, stream>>>(x2, ffno, g1n, g2n, f1, f2, out);
    (void)in_sizes; (void)n_in; (void)out_size; (void)ws_size;
}

// Round 4
// 681.531 us; speedup vs baseline: 5.1019x; 1.0076x over previous
//
#include <hip/hip_runtime.h>

#define TT 2048
#define BB 2
#define DD 1024
#define HH 16
#define HD 64
#define FF 4096
#define EE 8
#define SS (TT*BB)     // 4096 tokens
#define CAP 1024       // 2*ceil(S/E)
#define EPSF 1.1920929e-07f

typedef __attribute__((ext_vector_type(8))) short short8;
typedef __attribute__((ext_vector_type(4))) float floatx4;

static __device__ inline unsigned short f2bf(float f){
    unsigned int u = __float_as_uint(f);
    unsigned int r = (u + 0x7fffu + ((u>>16)&1u)) >> 16;
    return (unsigned short)r;
}
static __device__ inline float bf2f(unsigned short h){
    return __uint_as_float(((unsigned int)h)<<16);
}
// round-to-nearest split (weight prep / one-time epilogues)
static __device__ inline void split2(float x, unsigned short& h, unsigned short& l){
    unsigned short hh = f2bf(x);
    h = hh;
    l = f2bf(x - bf2f(hh));
}
// truncation split (hot path): residual still <= 2^-16 |x|
static __device__ inline void split2t(float x, unsigned short& h, unsigned short& l){
    unsigned int u = __float_as_uint(x);
    unsigned int hu = u & 0xffff0000u;
    h = (unsigned short)(hu>>16);
    float r = x - __uint_as_float(hu);
    l = (unsigned short)(__float_as_uint(r)>>16);
}
#define GETF4(v,j) ((j)==0?(v).x:(j)==1?(v).y:(j)==2?(v).z:(v).w)
#define GETU4(v,j) ((j)==0?(v).x:(j)==1?(v).y:(j)==2?(v).z:(v).w)

// ---------------- LayerNorm ---------------------------------------------------
__global__ __launch_bounds__(256) void ln_kernel(const float* __restrict__ x,
    const float* __restrict__ gam, const float* __restrict__ bet, float* __restrict__ o)
{
    int row = blockIdx.x;
    int tid = threadIdx.x;
    float4 v = ((const float4*)(x + (size_t)row*DD))[tid];
    float s  = v.x+v.y+v.z+v.w;
    float ss = v.x*v.x+v.y*v.y+v.z*v.z+v.w*v.w;
    __shared__ float r1[256], r2[256];
    r1[tid]=s; r2[tid]=ss;
    __syncthreads();
    for (int off=128; off>0; off>>=1){
        if (tid<off){ r1[tid]+=r1[tid+off]; r2[tid]+=r2[tid+off]; }
        __syncthreads();
    }
    float mean = r1[0] * (1.f/DD);
    float var  = r2[0] * (1.f/DD) - mean*mean;
    float inv  = 1.f / sqrtf(var + 1e-5f);
    float4 g = ((const float4*)gam)[tid];
    float4 b = ((const float4*)bet)[tid];
    float4 r;
    r.x = (v.x-mean)*inv*g.x + b.x;
    r.y = (v.y-mean)*inv*g.y + b.y;
    r.z = (v.z-mean)*inv*g.z + b.z;
    r.w = (v.w-mean)*inv*g.w + b.w;
    ((float4*)(o + (size_t)row*DD))[tid] = r;
}

// ---------------- plain bf16 MFMA GEMM (FFN; proven R2) ----------------------
template<bool RELU, bool OUTBF16>
__global__ __launch_bounds__(256) void gemm_mfma(
    const unsigned short* __restrict__ A, const unsigned short* __restrict__ Bt,
    const float* __restrict__ bias, float* __restrict__ Cf,
    unsigned short* __restrict__ Cb,
    int M, int N, int K, long wStride, int bStride, int rowsPerExp)
{
    __shared__ unsigned short As[128*64];
    __shared__ unsigned short Bs[128*64];
    const int tid = threadIdx.x, lane = tid&63;
    const int w = tid>>6, wr = w>>1, wc = w&1;
    const int m0 = blockIdx.y*128, n0 = blockIdx.x*128;
    const int e = m0 / rowsPerExp;
    const unsigned short* Bp = Bt + (size_t)e*wStride;
    const int srow = tid>>3, sslot = tid&7;
    floatx4 zf = {0.f,0.f,0.f,0.f};
    floatx4 acc[4][4];
    #pragma unroll
    for (int m=0;m<4;m++)
        #pragma unroll
        for (int n=0;n<4;n++) acc[m][n]=zf;

    short8 ar[4], br[4];
    #pragma unroll
    for (int i=0;i<4;i++){
        int r = srow + i*32;
        ar[i] = *(const short8*)(A  + (size_t)(m0+r)*K + sslot*8);
        br[i] = *(const short8*)(Bp + (size_t)(n0+r)*K + sslot*8);
    }
    const int NT = K/64;
    for (int kt=0; kt<NT; kt++){
        __syncthreads();
        #pragma unroll
        for (int i=0;i<4;i++){
            int r = srow + i*32;
            int off = r*64 + ((sslot ^ (r&7))<<3);
            *(short8*)(&As[off]) = ar[i];
            *(short8*)(&Bs[off]) = br[i];
        }
        __syncthreads();
        if (kt+1 < NT){
            int k0 = (kt+1)*64;
            #pragma unroll
            for (int i=0;i<4;i++){
                int r = srow + i*32;
                ar[i] = *(const short8*)(A  + (size_t)(m0+r)*K + k0 + sslot*8);
                br[i] = *(const short8*)(Bp + (size_t)(n0+r)*K + k0 + sslot*8);
            }
        }
        #pragma unroll
        for (int kk=0;kk<2;kk++){
            short8 af[4], bf[4];
            int kgrp = kk*4 + (lane>>4);
            #pragma unroll
            for (int m=0;m<4;m++){
                int rowa = wr*64 + m*16 + (lane&15);
                af[m] = *(const short8*)(&As[rowa*64 + ((kgrp ^ (rowa&7))<<3)]);
                int rowb = wc*64 + m*16 + (lane&15);
                bf[m] = *(const short8*)(&Bs[rowb*64 + ((kgrp ^ (rowb&7))<<3)]);
            }
            #pragma unroll
            for (int m=0;m<4;m++)
                #pragma unroll
                for (int n=0;n<4;n++)
                    acc[m][n] = __builtin_amdgcn_mfma_f32_16x16x32_bf16(af[m], bf[n], acc[m][n], 0,0,0);
        }
    }
    int colg = n0 + wc*64 + (lane&15);
    int rowg = m0 + wr*64 + ((lane>>4)<<2);
    #pragma unroll
    for (int n=0;n<4;n++){
        float bv = bias[e*bStride + colg + n*16];
        #pragma unroll
        for (int m=0;m<4;m++){
            #pragma unroll
            for (int i2=0;i2<4;i2++){
                float v = acc[m][n][i2] + bv;
                if (RELU) v = fmaxf(v, 0.f);
                size_t o = (size_t)(rowg + m*16 + i2)*N + colg + n*16;
                if (OUTBF16) Cb[o] = f2bf(v); else Cf[o] = v;
            }
        }
    }
}

// ---------------- split-bf16x3 MFMA GEMM (fp32-fidelity) ---------------------
// A f32 [M,K] (split in-kernel). Bhi/Blo bf16 [Ntot][K].
// QKV=true: Ntot=3072, chunk 0 -> f32 q (scale .125), chunk 1 -> split K hi/lo,
//           chunk 2 -> split V hi/lo.
// QKV=false: f32 out o0 with bias b0 + residual res.
template<bool QKV>
__global__ __launch_bounds__(256) void gemm_mfma_s(
    const float* __restrict__ A,
    const unsigned short* __restrict__ Bhi, const unsigned short* __restrict__ Blo,
    const float* __restrict__ b0, const float* __restrict__ b1p, const float* __restrict__ b2p,
    const float* __restrict__ res,
    float* __restrict__ o0,
    unsigned short* __restrict__ kh, unsigned short* __restrict__ kl,
    unsigned short* __restrict__ vh, unsigned short* __restrict__ vl,
    int M, int K)
{
    __shared__ unsigned short As[128*64];   // row: [hi k0..31 | lo k0..31] octet-swizzled
    __shared__ unsigned short Bs[128*64];
    const int tid = threadIdx.x, lane = tid&63;
    const int w = tid>>6, wr = w>>1, wc = w&1;
    const int m0 = blockIdx.y*128, n0 = blockIdx.x*128;
    const int row = tid>>1, khalf = tid&1;
    floatx4 zf = {0.f,0.f,0.f,0.f};
    floatx4 acc[4][4];
    #pragma unroll
    for (int m=0;m<4;m++)
        #pragma unroll
        for (int n=0;n<4;n++) acc[m][n]=zf;

    float4 aw0,aw1,aw2,aw3;
    short8 bwh0,bwh1,bwl0,bwl1;
    {
        const float* ap = A + (size_t)(m0+row)*K + khalf*16;
        aw0 = ((const float4*)ap)[0]; aw1 = ((const float4*)ap)[1];
        aw2 = ((const float4*)ap)[2]; aw3 = ((const float4*)ap)[3];
        const unsigned short* bh = Bhi + (size_t)(n0+row)*K + khalf*16;
        const unsigned short* bl = Blo + (size_t)(n0+row)*K + khalf*16;
        bwh0 = *(const short8*)(bh); bwh1 = *(const short8*)(bh+8);
        bwl0 = *(const short8*)(bl); bwl1 = *(const short8*)(bl+8);
    }
    const int NT = K/32;
    for (int kt=0; kt<NT; kt++){
        __syncthreads();
        {
            unsigned short h[16], l[16];
            #pragma unroll
            for (int j=0;j<4;j++){ split2t(GETF4(aw0,j), h[j],   l[j]); }
            #pragma unroll
            for (int j=0;j<4;j++){ split2t(GETF4(aw1,j), h[4+j], l[4+j]); }
            #pragma unroll
            for (int j=0;j<4;j++){ split2t(GETF4(aw2,j), h[8+j], l[8+j]); }
            #pragma unroll
            for (int j=0;j<4;j++){ split2t(GETF4(aw3,j), h[12+j],l[12+j]); }
            int base = row*64, sw = row&7;
            int g0 = khalf*2, g1 = khalf*2+1;
            *(short8*)(&As[base + ((g0^sw)<<3)])     = *(short8*)(&h[0]);
            *(short8*)(&As[base + ((g1^sw)<<3)])     = *(short8*)(&h[8]);
            *(short8*)(&As[base + (((g0+4)^sw)<<3)]) = *(short8*)(&l[0]);
            *(short8*)(&As[base + (((g1+4)^sw)<<3)]) = *(short8*)(&l[8]);
            *(short8*)(&Bs[base + ((g0^sw)<<3)])     = bwh0;
            *(short8*)(&Bs[base + ((g1^sw)<<3)])     = bwh1;
            *(short8*)(&Bs[base + (((g0+4)^sw)<<3)]) = bwl0;
            *(short8*)(&Bs[base + (((g1+4)^sw)<<3)]) = bwl1;
        }
        __syncthreads();
        if (kt+1 < NT){
            int k0 = (kt+1)*32;
            const float* ap = A + (size_t)(m0+row)*K + k0 + khalf*16;
            aw0 = ((const float4*)ap)[0]; aw1 = ((const float4*)ap)[1];
            aw2 = ((const float4*)ap)[2]; aw3 = ((const float4*)ap)[3];
            const unsigned short* bh = Bhi + (size_t)(n0+row)*K + k0 + khalf*16;
            const unsigned short* bl = Blo + (size_t)(n0+row)*K + k0 + khalf*16;
            bwh0 = *(const short8*)(bh); bwh1 = *(const short8*)(bh+8);
            bwl0 = *(const short8*)(bl); bwl1 = *(const short8*)(bl+8);
        }
        {
            int kg = lane>>4;
            short8 afh[4], afl[4], bfh[4], bfl[4];
            #pragma unroll
            for (int m=0;m<4;m++){
                int ra = wr*64 + m*16 + (lane&15);
                afh[m] = *(const short8*)(&As[ra*64 + ((kg ^ (ra&7))<<3)]);
                afl[m] = *(const short8*)(&As[ra*64 + (((kg+4) ^ (ra&7))<<3)]);
                int rb = wc*64 + m*16 + (lane&15);
                bfh[m] = *(const short8*)(&Bs[rb*64 + ((kg ^ (rb&7))<<3)]);
                bfl[m] = *(const short8*)(&Bs[rb*64 + (((kg+4) ^ (rb&7))<<3)]);
            }
            #pragma unroll
            for (int m=0;m<4;m++)
                #pragma unroll
                for (int n=0;n<4;n++){
                    acc[m][n] = __builtin_amdgcn_mfma_f32_16x16x32_bf16(afl[m], bfh[n], acc[m][n], 0,0,0);
                    acc[m][n] = __builtin_amdgcn_mfma_f32_16x16x32_bf16(afh[m], bfl[n], acc[m][n], 0,0,0);
                    acc[m][n] = __builtin_amdgcn_mfma_f32_16x16x32_bf16(afh[m], bfh[n], acc[m][n], 0,0,0);
                }
        }
    }
    int colg = n0 + wc*64 + (lane&15);
    int rowg = m0 + wr*64 + ((lane>>4)<<2);
    if (QKV){
        int chunk = n0>>10;
        int colc = colg & 1023;
        const float* bp = chunk==0 ? b0 : (chunk==1 ? b1p : b2p);
        #pragma unroll
        for (int n=0;n<4;n++){
            float bv = bp[colc + n*16];
            #pragma unroll
            for (int m=0;m<4;m++){
                #pragma unroll
                for (int i2=0;i2<4;i2++){
                    int r = rowg + m*16 + i2;
                    float v = acc[m][n][i2] + bv;
                    size_t off = (size_t)r*DD + colc + n*16;
                    if (chunk==0){
                        o0[off] = v*0.125f;
                    } else {
                        unsigned short hh, ll;
                        split2(v, hh, ll);
                        if (chunk==1){ kh[off]=hh; kl[off]=ll; }
                        else         { vh[off]=hh; vl[off]=ll; }
                    }
                }
            }
        }
    } else {
        #pragma unroll
        for (int n=0;n<4;n++){
            float bv = b0[colg + n*16];
            #pragma unroll
            for (int m=0;m<4;m++){
                #pragma unroll
                for (int i2=0;i2<4;i2++){
                    int r = rowg + m*16 + i2;
                    float v = acc[m][n][i2] + bv + res[(size_t)r*DD + colg + n*16];
                    o0[(size_t)r*DD + colg + n*16] = v;
                }
            }
        }
    }
}

// ---------------- split-bf16x3 MFMA flash attention --------------------------
// Grid (T/64, B*H), 256 thr = 4 waves x 16 q-rows. Q split in regs (once);
// K/V arrive PRE-SPLIT bf16 hi/lo -> staging is pure copy, no VALU split.
__global__ __launch_bounds__(256) void attn_mfma(const float* __restrict__ q,
    const unsigned short* __restrict__ khi, const unsigned short* __restrict__ klo,
    const unsigned short* __restrict__ vhi, const unsigned short* __restrict__ vlo,
    float* __restrict__ o)
{
    __shared__ unsigned short Kh[64*64], Kl[64*64];
    __shared__ unsigned short Vh[64*64], Vl[64*64];
    __shared__ unsigned short Ph[4*16*64], Pl[4*16*64];
    const int tid = threadIdx.x, lane = tid&63, w = tid>>6;
    const int t0 = blockIdx.x*64;
    const int b = blockIdx.y>>4, h = blockIdx.y&15;

    // Q fragments in registers: row=lane&15 (wave strip), k=kk*32+(lane>>4)*8+j
    short8 qh[2], ql[2];
    #pragma unroll
    for (int kk=0;kk<2;kk++){
        const float* qp = q + ((size_t)(t0 + 16*w + (lane&15))*BB + b)*DD + h*64 + kk*32 + (lane>>4)*8;
        float4 f0 = ((const float4*)qp)[0];
        float4 f1 = ((const float4*)qp)[1];
        unsigned short hh[8], ll[8];
        #pragma unroll
        for (int j=0;j<4;j++){ split2(GETF4(f0,j), hh[j], ll[j]); }
        #pragma unroll
        for (int j=0;j<4;j++){ split2(GETF4(f1,j), hh[4+j], ll[4+j]); }
        qh[kk] = *(short8*)hh; ql[kk] = *(short8*)ll;
    }

    // staging indices
    const int kr = tid>>2, kq = tid&3;            // K: row kr, d-quarter kq
    const int vs0 = (tid&15)*4, vd0 = (tid>>4)*4; // V: 4 tokens x 4 d
    short8 kwh0,kwh1,kwl0,kwl1;
    ushort4 vwh[4], vwl[4];
    {
        const unsigned short* kp = khi + ((size_t)kr*BB + b)*DD + h*64 + kq*16;
        const unsigned short* lp = klo + ((size_t)kr*BB + b)*DD + h*64 + kq*16;
        kwh0 = *(const short8*)(kp); kwh1 = *(const short8*)(kp+8);
        kwl0 = *(const short8*)(lp); kwl1 = *(const short8*)(lp+8);
        #pragma unroll
        for (int i=0;i<4;i++){
            size_t vo = ((size_t)(vs0+i)*BB + b)*DD + h*64 + vd0;
            vwh[i] = *(const ushort4*)(vhi + vo);
            vwl[i] = *(const ushort4*)(vlo + vo);
        }
    }

    float m_st[4] = {-3.0e38f,-3.0e38f,-3.0e38f,-3.0e38f};
    float l_st[4] = {0.f,0.f,0.f,0.f};
    floatx4 zf = {0.f,0.f,0.f,0.f};
    floatx4 oacc[4];
    #pragma unroll
    for (int n=0;n<4;n++) oacc[n]=zf;

    for (int s0=0; s0<TT; s0+=64){
        __syncthreads();
        // ---- stage K (copy) ----
        {
            int base = kr*64, sw = kr&7;
            int g0 = kq*2, g1 = kq*2+1;
            *(short8*)(&Kh[base + ((g0^sw)<<3)]) = kwh0;
            *(short8*)(&Kh[base + ((g1^sw)<<3)]) = kwh1;
            *(short8*)(&Kl[base + ((g0^sw)<<3)]) = kwl0;
            *(short8*)(&Kl[base + ((g1^sw)<<3)]) = kwl1;
        }
        // ---- stage V transposed (copy + 4x4 reg transpose) ----
        {
            int g = vs0>>3, so = vs0&7;
            #pragma unroll
            for (int j=0;j<4;j++){
                int d = vd0 + j;
                ushort4 hv, lv;
                hv.x=GETU4(vwh[0],j); hv.y=GETU4(vwh[1],j); hv.z=GETU4(vwh[2],j); hv.w=GETU4(vwh[3],j);
                lv.x=GETU4(vwl[0],j); lv.y=GETU4(vwl[1],j); lv.z=GETU4(vwl[2],j); lv.w=GETU4(vwl[3],j);
                int off = d*64 + ((g ^ (d&7))<<3) + so;
                *(ushort4*)(&Vh[off]) = hv;
                *(ushort4*)(&Vl[off]) = lv;
            }
        }
        __syncthreads();
        // ---- prefetch next K/V tile ----
        if (s0+64 < TT){
            const unsigned short* kp = khi + ((size_t)(s0+64+kr)*BB + b)*DD + h*64 + kq*16;
            const unsigned short* lp = klo + ((size_t)(s0+64+kr)*BB + b)*DD + h*64 + kq*16;
            kwh0 = *(const short8*)(kp); kwh1 = *(const short8*)(kp+8);
            kwl0 = *(const short8*)(lp); kwl1 = *(const short8*)(lp+8);
            #pragma unroll
            for (int i=0;i<4;i++){
                size_t vo = ((size_t)(s0+64+vs0+i)*BB + b)*DD + h*64 + vd0;
                vwh[i] = *(const ushort4*)(vhi + vo);
                vwl[i] = *(const ushort4*)(vlo + vo);
            }
        }
        // ---- QK^T: S strip 16x64, 3-term split ----
        floatx4 sacc[4];
        #pragma unroll
        for (int n=0;n<4;n++){
            floatx4 s = zf;
            #pragma unroll
            for (int kk=0;kk<2;kk++){
                int g = kk*4 + (lane>>4);
                int rb = n*16 + (lane&15);
                short8 kbh = *(const short8*)(&Kh[rb*64 + ((g ^ (rb&7))<<3)]);
                short8 kbl = *(const short8*)(&Kl[rb*64 + ((g ^ (rb&7))<<3)]);
                s = __builtin_amdgcn_mfma_f32_16x16x32_bf16(ql[kk], kbh, s, 0,0,0);
                s = __builtin_amdgcn_mfma_f32_16x16x32_bf16(qh[kk], kbl, s, 0,0,0);
                s = __builtin_amdgcn_mfma_f32_16x16x32_bf16(qh[kk], kbh, s, 0,0,0);
            }
            sacc[n] = s;
        }
        // ---- online softmax ----
        float mx[4];
        #pragma unroll
        for (int r=0;r<4;r++)
            mx[r] = fmaxf(fmaxf(sacc[0][r], sacc[1][r]), fmaxf(sacc[2][r], sacc[3][r]));
        #pragma unroll
        for (int sh=1; sh<16; sh<<=1){
            #pragma unroll
            for (int r=0;r<4;r++) mx[r] = fmaxf(mx[r], __shfl_xor(mx[r], sh));
        }
        float corr[4];
        #pragma unroll
        for (int r=0;r<4;r++){
            float nm = fmaxf(m_st[r], mx[r]);
            corr[r] = __expf(m_st[r] - nm);
            m_st[r] = nm;
        }
        float ts[4] = {0.f,0.f,0.f,0.f};
        #pragma unroll
        for (int n=0;n<4;n++){
            #pragma unroll
            for (int r=0;r<4;r++){
                float p = __expf(sacc[n][r] - m_st[r]);
                ts[r] += p;
                unsigned short ph, pl;
                split2t(p, ph, pl);
                int q2 = ((lane>>4)<<2) + r;
                int s2 = n*16 + (lane&15);
                int off = w*1024 + q2*64 + (((s2>>3) ^ (q2&7))<<3) + (s2&7);
                Ph[off] = ph; Pl[off] = pl;
            }
        }
        #pragma unroll
        for (int sh=1; sh<16; sh<<=1){
            #pragma unroll
            for (int r=0;r<4;r++) ts[r] += __shfl_xor(ts[r], sh);
        }
        #pragma unroll
        for (int r=0;r<4;r++) l_st[r] = l_st[r]*corr[r] + ts[r];
        #pragma unroll
        for (int n=0;n<4;n++)
            #pragma unroll
            for (int r=0;r<4;r++) oacc[n][r] *= corr[r];
        // ---- PV: O strip 16x64, 3-term split ----
        #pragma unroll
        for (int kk=0;kk<2;kk++){
            int g = kk*4 + (lane>>4);
            int rq = lane&15;
            short8 pah = *(const short8*)(&Ph[w*1024 + rq*64 + ((g ^ (rq&7))<<3)]);
            short8 pal = *(const short8*)(&Pl[w*1024 + rq*64 + ((g ^ (rq&7))<<3)]);
            #pragma unroll
            for (int n=0;n<4;n++){
                int rd = n*16 + (lane&15);
                short8 vbh = *(const short8*)(&Vh[rd*64 + ((g ^ (rd&7))<<3)]);
                short8 vbl = *(const short8*)(&Vl[rd*64 + ((g ^ (rd&7))<<3)]);
                oacc[n] = __builtin_amdgcn_mfma_f32_16x16x32_bf16(pal, vbh, oacc[n], 0,0,0);
                oacc[n] = __builtin_amdgcn_mfma_f32_16x16x32_bf16(pah, vbl, oacc[n], 0,0,0);
                oacc[n] = __builtin_amdgcn_mfma_f32_16x16x32_bf16(pah, vbh, oacc[n], 0,0,0);
            }
        }
    }
    // ---- epilogue ----
    float il[4];
    #pragma unroll
    for (int r=0;r<4;r++) il[r] = 1.f/l_st[r];
    int qrow = t0 + 16*w + ((lane>>4)<<2);
    #pragma unroll
    for (int n=0;n<4;n++){
        #pragma unroll
        for (int r=0;r<4;r++){
            o[((size_t)(qrow+r)*BB + b)*DD + h*64 + n*16 + (lane&15)] = oacc[n][r]*il[r];
        }
    }
}

// ---------------- transpose+convert bf16 (FFN weights; proven R2) ------------
__global__ __launch_bounds__(256) void transpose_bf16_k(const float* __restrict__ in,
    unsigned short* __restrict__ outp, int R, int C)
{
    __shared__ float t[64][65];
    int e = blockIdx.z;
    const float* ip = in + (size_t)e*R*C;
    unsigned short* op = outp + (size_t)e*R*C;
    int r0 = blockIdx.y*64, c0 = blockIdx.x*64;
    int tid = threadIdx.x;
    #pragma unroll
    for (int i=0;i<4;i++){
        int ch = i*256 + tid;
        int r = ch>>4, c4 = (ch&15)*4;
        float4 v = *(const float4*)(ip + (size_t)(r0+r)*C + c0 + c4);
        t[r][c4+0]=v.x; t[r][c4+1]=v.y; t[r][c4+2]=v.z; t[r][c4+3]=v.w;
    }
    __syncthreads();
    #pragma unroll
    for (int i=0;i<4;i++){
        int ch = i*256 + tid;
        int rr = ch>>4, c4 = (ch&15)*4;
        ushort4 o;
        o.x = f2bf(t[c4+0][rr]); o.y = f2bf(t[c4+1][rr]);
        o.z = f2bf(t[c4+2][rr]); o.w = f2bf(t[c4+3][rr]);
        *(ushort4*)(op + (size_t)(c0+rr)*R + r0 + c4) = o;
    }
}

// ---------------- transpose + split hi/lo (projection weights) ---------------
__global__ __launch_bounds__(256) void transpose_split_k(const float* __restrict__ in,
    unsigned short* __restrict__ oh, unsigned short* __restrict__ ol, int R, int C)
{
    __shared__ float t[64][65];
    int r0 = blockIdx.y*64, c0 = blockIdx.x*64;
    int tid = threadIdx.x;
    #pragma unroll
    for (int i=0;i<4;i++){
        int ch = i*256 + tid;
        int r = ch>>4, c4 = (ch&15)*4;
        float4 v = *(const float4*)(in + (size_t)(r0+r)*C + c0 + c4);
        t[r][c4+0]=v.x; t[r][c4+1]=v.y; t[r][c4+2]=v.z; t[r][c4+3]=v.w;
    }
    __syncthreads();
    #pragma unroll
    for (int i=0;i<4;i++){
        int ch = i*256 + tid;
        int rr = ch>>4, c4 = (ch&15)*4;
        ushort4 hv, lv;
        split2(t[c4+0][rr], hv.x, lv.x);
        split2(t[c4+1][rr], hv.y, lv.y);
        split2(t[c4+2][rr], hv.z, lv.z);
        split2(t[c4+3][rr], hv.w, lv.w);
        size_t off = (size_t)(c0+rr)*R + r0 + c4;
        *(ushort4*)(oh + off) = hv;
        *(ushort4*)(ol + off) = lv;
    }
}

// ---------------- gather dispatch buffer -------------------------------------
__global__ __launch_bounds__(256) void gather_bf16_k(const float* __restrict__ h2,
    const int* __restrict__ s2r, unsigned short* __restrict__ buf)
{
    int s = blockIdx.x; int row = s2r[s]; int c = threadIdx.x;
    float4 v = make_float4(0.f,0.f,0.f,0.f);
    if (row>=0) v = *(const float4*)(h2 + (size_t)row*DD + c*4);
    ushort4 o;
    o.x=f2bf(v.x); o.y=f2bf(v.y); o.z=f2bf(v.z); o.w=f2bf(v.w);
    *(ushort4*)(buf + (size_t)s*DD + c*4) = o;
}

// ---------------- Routing (unchanged) ----------------------------------------
__global__ __launch_bounds__(256) void route_kernel(const float* __restrict__ h2,
    const float* __restrict__ wgm, float* __restrict__ gates,
    int* __restrict__ idx1, int* __restrict__ idx2,
    float* __restrict__ g1, float* __restrict__ g2)
{
    int wid = threadIdx.x >> 6, lane = threadIdx.x & 63;
    int s = blockIdx.x*4 + wid;
    int row = (s % TT)*BB + (s / TT);
    const float* hr = h2 + (size_t)row*DD;
    float acc[EE] = {};
    #pragma unroll
    for (int c=0;c<16;c++){
        int d = c*64 + lane;
        float xv = hr[d];
        const float* wr = wgm + (size_t)d*EE;
        #pragma unroll
        for (int e2=0;e2<EE;e2++) acc[e2] += xv * wr[e2];
    }
    #pragma unroll
    for (int off=32; off>0; off>>=1){
        #pragma unroll
        for (int e2=0;e2<EE;e2++) acc[e2] += __shfl_down(acc[e2], off);
    }
    if (lane==0){
        float mx = acc[0];
        #pragma unroll
        for (int e2=1;e2<EE;e2++) mx = fmaxf(mx, acc[e2]);
        float ex[EE]; float sum=0.f;
        #pragma unroll
        for (int e2=0;e2<EE;e2++){ ex[e2] = __expf(acc[e2]-mx); sum += ex[e2]; }
        float inv = 1.f/sum;
        int i1=0; float bv1=acc[0];
        #pragma unroll
        for (int e2=1;e2<EE;e2++){ if (acc[e2] > bv1){ bv1=acc[e2]; i1=e2; } }
        int i2=-1; float bv2=-3.0e38f;
        #pragma unroll
        for (int e2=0;e2<EE;e2++){ if (e2!=i1 && acc[e2] > bv2){ bv2=acc[e2]; i2=e2; } }
        #pragma unroll
        for (int e2=0;e2<EE;e2++) gates[(size_t)s*EE + e2] = ex[e2]*inv;
        idx1[s]=i1; idx2[s]=i2;
        g1[s]=ex[i1]*inv; g2[s]=ex[i2]*inv;
    }
}

// ---------------- Single-block deterministic scan (unchanged) ----------------
__global__ __launch_bounds__(256) void scan_kernel(
    const float* __restrict__ gates, const int* __restrict__ idx1, const int* __restrict__ idx2,
    const float* __restrict__ g1, const float* __restrict__ g2,
    float* __restrict__ g1n, float* __restrict__ g2n,
    int* __restrict__ f1, int* __restrict__ f2, int* __restrict__ slot2row,
    float* __restrict__ laux)
{
    __shared__ int i1s[SS];
    __shared__ int i2s[SS];
    __shared__ int cnt1[256][EE];
    __shared__ int cnt2[256][EE];
    __shared__ float gsum[256][EE];
    __shared__ int tot1[EE];
    int tid = threadIdx.x;
    for (int i=tid;i<EE*CAP;i+=256) slot2row[i] = -1;
    for (int i=tid;i<SS;i+=256){ i1s[i]=idx1[i]; i2s[i]=idx2[i]; }
    __syncthreads();
    int c1l[EE]={}, c2l[EE]={};
    float gl[EE]={};
    int base = tid*16;
    for (int qq=0;qq<16;qq++){
        int s = base+qq;
        c1l[i1s[s]]++; c2l[i2s[s]]++;
        #pragma unroll
        for (int e2=0;e2<EE;e2++) gl[e2] += gates[(size_t)s*EE+e2];
    }
    #pragma unroll
    for (int e2=0;e2<EE;e2++){ cnt1[tid][e2]=c1l[e2]; cnt2[tid][e2]=c2l[e2]; gsum[tid][e2]=gl[e2]; }
    __syncthreads();
    if (tid < EE){
        int e2 = tid;
        int run=0;
        for (int t=0;t<256;t++){ int tmp=cnt1[t][e2]; cnt1[t][e2]=run; run+=tmp; }
        tot1[e2]=run;
        run=0;
        for (int t=0;t<256;t++){ int tmp=cnt2[t][e2]; cnt2[t][e2]=run; run+=tmp; }
        float gr=0.f;
        for (int t=0;t<256;t++) gr += gsum[t][e2];
        gsum[0][e2]=gr;
    }
    __syncthreads();
    int p1[EE], p2[EE];
    #pragma unroll
    for (int e2=0;e2<EE;e2++){ p1[e2]=cnt1[tid][e2]; p2[e2]=cnt2[tid][e2]+tot1[e2]; }
    for (int qq=0;qq<16;qq++){
        int s = base+qq;
        int e1 = i1s[s], e2v = i2s[s];
        int pos1 = p1[e1]++;
        int pos2 = p2[e2v]++;
        float gv1 = g1[s], gv2 = g2[s];
        float gm1 = (pos1<CAP)? gv1 : 0.f;
        float gm2 = (pos2<CAP)? gv2 : 0.f;
        float den = fmaxf(gm1+gm2, EPSF);
        g1n[s] = gm1/den; g2n[s] = gm2/den;
        int ff1 = e1*CAP + (pos1<CAP?pos1:CAP-1);
        int ff2 = e2v*CAP + (pos2<CAP?pos2:CAP-1);
        f1[s]=ff1; f2[s]=ff2;
        int hrow = (s % TT)*BB + (s / TT);
        if (pos1<CAP) slot2row[ff1]=hrow;
        if (pos2<CAP) slot2row[ff2]=hrow;
    }
    if (tid==0){
        float a=0.f;
        #pragma unroll
        for (int e2=0;e2<EE;e2++) a += (gsum[0][e2]*(1.f/SS)) * ((float)tot1[e2]*(1.f/SS));
        laux[0] = a * (float)EE;
    }
}

// ---------------- Combine (unchanged) ----------------------------------------
__global__ __launch_bounds__(256) void combine_kernel(const float* __restrict__ x2,
    const float* __restrict__ eout, const float* __restrict__ g1n, const float* __restrict__ g2n,
    const int* __restrict__ f1, const int* __restrict__ f2, float* __restrict__ out)
{
    int s = blockIdx.x;
    float a = g1n[s], b = g2n[s];
    int s1 = f1[s], s2 = f2[s];
    int row = (s % TT)*BB + (s / TT);
    int c = threadIdx.x;
    float4 o1 = ((const float4*)(eout + (size_t)s1*DD))[c];
    float4 o2 = ((const float4*)(eout + (size_t)s2*DD))[c];
    float4 xr = ((const float4*)(x2 + (size_t)row*DD))[c];
    float4 r;
    r.x = xr.x + a*o1.x + b*o2.x;
    r.y = xr.y + a*o1.y + b*o2.y;
    r.z = xr.z + a*o1.z + b*o2.z;
    r.w = xr.w + a*o1.w + b*o2.w;
    ((float4*)(out + (size_t)row*DD))[c] = r;
}

extern "C" void kernel_launch(void* const* d_in, const int* in_sizes, int n_in,
                              void* d_out, int out_size, void* d_ws, size_t ws_size,
                              hipStream_t stream)
{
    const float* x    = (const float*)d_in[0];
    const float* Wq   = (const float*)d_in[1];
    const float* bq   = (const float*)d_in[2];
    const float* Wk   = (const float*)d_in[3];
    const float* bk   = (const float*)d_in[4];
    const float* Wv   = (const float*)d_in[5];
    const float* bv   = (const float*)d_in[6];
    const float* Wo   = (const float*)d_in[7];
    const float* bo   = (const float*)d_in[8];
    const float* ln1g = (const float*)d_in[9];
    const float* ln1b = (const float*)d_in[10];
    const float* ln2g = (const float*)d_in[11];
    const float* ln2b = (const float*)d_in[12];
    const float* wgm  = (const float*)d_in[13];
    const float* W1   = (const float*)d_in[14];
    const float* b1   = (const float*)d_in[15];
    const float* W2   = (const float*)d_in[16];
    const float* b2   = (const float*)d_in[17];
    float* out = (float*)d_out;

    char* w = (char*)d_ws;
    float*          h1   = (float*)(w);                        // 16MB (LN1 out / attn out)
    float*          qb   = (float*)(w + ((size_t)16<<20));     // 16MB (q f32, then h2)
    unsigned short* Khg  = (unsigned short*)(w + ((size_t)32<<20));   // 8MB bf16 [4096][1024]
    unsigned short* Klg  = (unsigned short*)(w + ((size_t)40<<20));   // 8MB
    unsigned short* Vhg  = (unsigned short*)(w + ((size_t)48<<20));   // 8MB
    unsigned short* Vlg  = (unsigned short*)(w + ((size_t)56<<20));   // 8MB
    float*          x2   = (float*)(w + ((size_t)64<<20));     // 16MB
    unsigned short* bufb = (unsigned short*)(w + ((size_t)80<<20));   // 16MB bf16 dispatch
    unsigned short* hb   = (unsigned short*)(w + ((size_t)96<<20));   // 64MB bf16 FFN1 out
    unsigned short* Bqkv_hi = (unsigned short*)(w + ((size_t)96<<20));   // 6MB (dead before FFN1)
    unsigned short* Bqkv_lo = (unsigned short*)(w + ((size_t)102<<20));  // 6MB
    unsigned short* Bo_hi   = (unsigned short*)(w + ((size_t)108<<20));  // 2MB
    unsigned short* Bo_lo   = (unsigned short*)(w + ((size_t)110<<20));  // 2MB
    unsigned short* W1t  = (unsigned short*)(w + ((size_t)160<<20));  // 64MB
    unsigned short* W2t  = (unsigned short*)(w + ((size_t)224<<20));  // 64MB
    float*          ffno = (float*)(w + ((size_t)32<<20));     // 32MB f32 (reuses K/V split bufs)
    char*  sm   = w + ((size_t)288<<20);
    float* gates   = (float*)(sm);                sm += (size_t)SS*EE*4;
    int*   idx1    = (int*)(sm);                  sm += SS*4;
    int*   idx2    = (int*)(sm);                  sm += SS*4;
    float* g1      = (float*)(sm);                sm += SS*4;
    float* g2      = (float*)(sm);                sm += SS*4;
    float* g1n     = (float*)(sm);                sm += SS*4;
    float* g2n     = (float*)(sm);                sm += SS*4;
    int*   f1      = (int*)(sm);                  sm += SS*4;
    int*   f2      = (int*)(sm);                  sm += SS*4;
    int*   slot2row= (int*)(sm);                  sm += EE*CAP*4;

    // 0. weight prep
    transpose_bf16_k<<<dim3(FF/64, DD/64, EE), 256, 0, stream>>>(W1, W1t, DD, FF);
    transpose_bf16_k<<<dim3(DD/64, FF/64, EE), 256, 0, stream>>>(W2, W2t, FF, DD);
    transpose_split_k<<<dim3(16,16), 256, 0, stream>>>(Wq, Bqkv_hi,                   Bqkv_lo,                   DD, DD);
    transpose_split_k<<<dim3(16,16), 256, 0, stream>>>(Wk, Bqkv_hi + (size_t)DD*DD,   Bqkv_lo + (size_t)DD*DD,   DD, DD);
    transpose_split_k<<<dim3(16,16), 256, 0, stream>>>(Wv, Bqkv_hi + (size_t)2*DD*DD, Bqkv_lo + (size_t)2*DD*DD, DD, DD);
    transpose_split_k<<<dim3(16,16), 256, 0, stream>>>(Wo, Bo_hi, Bo_lo, DD, DD);
    // 1. LN1
    ln_kernel<<<SS, 256, 0, stream>>>(x, ln1g, ln1b, h1);
    // 2. fused QKV projection; K,V written pre-split bf16 hi/lo
    gemm_mfma_s<true><<<dim3(24, SS/128), 256, 0, stream>>>(
        h1, Bqkv_hi, Bqkv_lo, bq, bk, bv, nullptr, qb, Khg, Klg, Vhg, Vlg, SS, DD);
    // 3. attention (split-bf16x3 MFMA flash) -> h1
    attn_mfma<<<dim3(TT/64, BB*HH), 256, 0, stream>>>(qb, Khg, Klg, Vhg, Vlg, h1);
    // 4. O-projection + residual -> x2
    gemm_mfma_s<false><<<dim3(8, SS/128), 256, 0, stream>>>(
        h1, Bo_hi, Bo_lo, bo, bo, bo, x, x2, nullptr, nullptr, nullptr, nullptr, SS, DD);
    // 5. LN2 -> h2 (qb)
    ln_kernel<<<SS, 256, 0, stream>>>(x2, ln2g, ln2b, qb);
    // 6. routing
    route_kernel<<<SS/4, 256, 0, stream>>>(qb, wgm, gates, idx1, idx2, g1, g2);
    // 7. scan
    scan_kernel<<<1, 256, 0, stream>>>(gates, idx1, idx2, g1, g2,
        g1n, g2n, f1, f2, slot2row, out + (size_t)SS*DD);
    // 8. gather dispatch buffer
    gather_bf16_k<<<EE*CAP, 256, 0, stream>>>(qb, slot2row, bufb);
    // 9. expert FFN (plain bf16 MFMA)
    gemm_mfma<true,true><<<dim3(FF/128, (EE*CAP)/128), 256, 0, stream>>>(
        bufb, W1t, b1, nullptr, hb, EE*CAP, FF, DD, (long)FF*DD, FF, CAP);
    gemm_mfma<false,false><<<dim3(DD/128, (EE*CAP)/128), 256, 0, stream>>>(
        hb, W2t, b2, ffno, nullptr, EE*CAP, DD, FF, (long)DD*FF, DD, CAP);
    // 10. combine + residual
    combine_kernel<<<SS, 256, 0, stream>>>(x2, ffno, g1n, g2n, f1, f2, out);
    (void)in_sizes; (void)n_in; (void)out_size; (void)ws_size;
}